// Round 19
// baseline (598.217 us; speedup 1.0000x reference)
//
#include <hip/hip_runtime.h>
#include <math.h>

typedef __attribute__((ext_vector_type(8))) short bf16x8;
typedef __attribute__((ext_vector_type(4))) float f32x4;

__device__ __forceinline__ float b2f(unsigned short u) {
    union { unsigned u32; float f; } x; x.u32 = (unsigned)u << 16; return x.f;
}
__device__ __forceinline__ unsigned short f2b(float f) {
    union { float f; unsigned u32; } x; x.f = f;
    unsigned u = x.u32;
    unsigned r = (u + 0x7fffu + ((u >> 16) & 1u)) >> 16;   // RNE
    return (unsigned short)r;
}

// f32 -> OCP e4m3fn, RNE, clamp to +-448, subnormals exact.
__device__ __forceinline__ unsigned char f2e4m3(float f) {
    union { float f; unsigned u; } x; x.f = f;
    unsigned s = (x.u >> 24) & 0x80;
    x.u &= 0x7fffffff;
    if (!(x.f == x.f)) return (unsigned char)(s | 0x7e);
    if (x.f >= 448.f) return (unsigned char)(s | 0x7e);
    if (x.f < 0.015625f) {                       // subnormal: m * 2^-9, RNE
        int m = (int)rintf(x.f * 512.f);
        if (m >= 8) return (unsigned char)(s | 0x08);
        return (unsigned char)(s | (unsigned)m);
    }
    unsigned exp = x.u >> 23;
    unsigned mant = x.u & 0x7fffff;
    unsigned m3 = mant >> 20;
    unsigned rb = (mant >> 19) & 1u;
    unsigned sticky = (mant & 0x7ffffu) ? 1u : 0u;
    m3 += rb & (sticky | (m3 & 1u));
    if (m3 == 8) { m3 = 0; exp++; }
    unsigned e4 = exp - 120;                     // bias 7
    if (e4 >= 15 && m3 > 6) { e4 = 15; m3 = 6; } // stay <= 448
    return (unsigned char)(s | (e4 << 3) | m3);
}

// decode one packed fp8 byte-lane j of word w -> f32 scaled by 2^-120 (subnormals exact)
__device__ __forceinline__ float dec_fp8(unsigned w, int j) {
    union { unsigned u; float f; } t;
    unsigned b = (w >> (j * 8)) & 0xffu;
    t.u = ((b & 0x80u) << 24) | ((b & 0x7fu) << 20);
    return t.f;
}

// accumulate 4 fp8 v-values (packed in vw) scaled by exs (= ex * 2^120)
__device__ __forceinline__ void acc4_fp8(float exs, unsigned vw, float4& acc) {
    acc.x += exs * dec_fp8(vw, 0);
    acc.y += exs * dec_fp8(vw, 1);
    acc.z += exs * dec_fp8(vw, 2);
    acc.w += exs * dec_fp8(vw, 3);
}

// q (f32x4) dot 4 fp8 k-values -> partial, scaled 2^-120
__device__ __forceinline__ float dot4_fp8(const float4& qv, unsigned kw) {
    return qv.x * dec_fp8(kw, 0) + qv.y * dec_fp8(kw, 1)
         + qv.z * dec_fp8(kw, 2) + qv.w * dec_fp8(kw, 3);
}

__device__ __forceinline__ f32x4 mfma16(bf16x8 a, bf16x8 b, f32x4 c) {
    return __builtin_amdgcn_mfma_f32_16x16x32_bf16(a, b, c, 0, 0, 0);
}

// async global->LDS, 16B per lane: lds dest = uniform base + lane*16, global src per-lane.
__device__ __forceinline__ void async_copy16(const unsigned* g, void* l) {
    __builtin_amdgcn_global_load_lds(
        (const __attribute__((address_space(1))) unsigned*)g,
        (__attribute__((address_space(3))) unsigned*)l, 16, 0, 0);
}

// ---------------- CSR scan pieces ----------------

__global__ __launch_bounds__(256) void scanA_k(const int* __restrict__ deg, int* __restrict__ rowptr,
                                               int* __restrict__ partials, int N) {
    __shared__ int sh[256];
    int t = threadIdx.x;
    int base = blockIdx.x * 1024 + t * 4;
    int v0 = 0, v1 = 0, v2 = 0, v3 = 0;
    if (base + 0 < N) v0 = deg[base + 0];
    if (base + 1 < N) v1 = deg[base + 1];
    if (base + 2 < N) v2 = deg[base + 2];
    if (base + 3 < N) v3 = deg[base + 3];
    sh[t] = v0 + v1 + v2 + v3;
    __syncthreads();
    for (int off = 1; off < 256; off <<= 1) {
        int add = (t >= off) ? sh[t - off] : 0;
        __syncthreads();
        sh[t] += add;
        __syncthreads();
    }
    int run = (t > 0) ? sh[t - 1] : 0;
    if (base + 0 < N) rowptr[base + 0] = run; run += v0;
    if (base + 1 < N) rowptr[base + 1] = run; run += v1;
    if (base + 2 < N) rowptr[base + 2] = run; run += v2;
    if (base + 3 < N) rowptr[base + 3] = run;
    if (t == 255) partials[blockIdx.x] = sh[255];
}

__global__ void scanB_k(int* partials, int nch) {
    if (threadIdx.x == 0 && blockIdx.x == 0) {
        int run = 0;
        for (int i = 0; i < nch; ++i) { int x = partials[i]; partials[i] = run; run += x; }
        partials[nch] = run;
    }
}

__global__ __launch_bounds__(256) void addoff_k(int* __restrict__ rowptr, const int* __restrict__ partials,
                                                int N, int nch) {
    int t = threadIdx.x;
    int off = partials[blockIdx.x];
    int base = blockIdx.x * 1024;
    for (int i = 0; i < 4; ++i) {
        int idx = base + t + i * 256;
        if (idx < N) rowptr[idx] += off;
    }
    if (blockIdx.x == 0 && t == 0) rowptr[N] = partials[nch];
}

__global__ __launch_bounds__(256) void scatter_k(const int* __restrict__ src, const int* __restrict__ dst,
                                                 const int* __restrict__ rowptr, int* __restrict__ cnt,
                                                 int* __restrict__ srcid, int E) {
    int e = blockIdx.x * 256 + threadIdx.x;
    if (e < E) {
        int d = dst[e];
        int pos = rowptr[d] + atomicAdd(&cnt[d], 1);
        srcid[pos] = src[e];
    }
}

// ---------------- merged prologue: hist + cvt(interleaved) + wprep x2 ----------------
// X interleaved layout: row = 2*Cin shorts; 8-col group g: hi8 at [g*16, g*16+8), lo8 at +8.

__global__ __launch_bounds__(256) void prep_k(
    const int* __restrict__ dst, int* __restrict__ deg, int E, int histB,
    const float* __restrict__ x, unsigned short* __restrict__ Xc, int ngrp, int cvtB,
    const float* __restrict__ Wq1, const float* __restrict__ Wk1,
    const float* __restrict__ Wv1, const float* __restrict__ Ws1,
    unsigned* __restrict__ fhi1, unsigned* __restrict__ flo1, int w1B,
    const float* __restrict__ Wq2, const float* __restrict__ Wk2,
    const float* __restrict__ Wv2, const float* __restrict__ Ws2,
    unsigned* __restrict__ fhi2, unsigned* __restrict__ flo2)
{
    int b = blockIdx.x;
    int tid = threadIdx.x;
    if (b < histB) {
        int e = b * 256 + tid;
        if (e < E) atomicAdd(&deg[dst[e]], 1);
        return;
    }
    b -= histB;
    if (b < cvtB) {
        int gi = b * 256 + tid;   // group of 8 f32 -> hi8|lo8 (32B contiguous)
        if (gi < ngrp) {
            const float* xp = x + (size_t)gi * 8;
            float4 a0 = *(const float4*)xp;
            float4 a1 = *(const float4*)(xp + 4);
            unsigned short* op = Xc + (size_t)gi * 16;
            ushort4 h0, h1, L0, L1;
            h0.x = f2b(a0.x); L0.x = f2b(a0.x - b2f(h0.x));
            h0.y = f2b(a0.y); L0.y = f2b(a0.y - b2f(h0.y));
            h0.z = f2b(a0.z); L0.z = f2b(a0.z - b2f(h0.z));
            h0.w = f2b(a0.w); L0.w = f2b(a0.w - b2f(h0.w));
            h1.x = f2b(a1.x); L1.x = f2b(a1.x - b2f(h1.x));
            h1.y = f2b(a1.y); L1.y = f2b(a1.y - b2f(h1.y));
            h1.z = f2b(a1.z); L1.z = f2b(a1.z - b2f(h1.z));
            h1.w = f2b(a1.w); L1.w = f2b(a1.w - b2f(h1.w));
            *(ushort4*)(op)      = h0;
            *(ushort4*)(op + 4)  = h1;
            *(ushort4*)(op + 8)  = L0;
            *(ushort4*)(op + 12) = L1;
        }
        return;
    }
    b -= cvtB;
    const float *Wq, *Wk, *Wv, *Ws; unsigned *fhi, *flo; int ksteps, idx;
    if (b < w1B) {
        Wq = Wq1; Wk = Wk1; Wv = Wv1; Ws = Ws1; fhi = fhi1; flo = flo1;
        ksteps = 4; idx = b * 256 + tid;
        if (idx >= 26 * 4 * 64 * 4) return;
    } else {
        Wq = Wq2; Wk = Wk2; Wv = Wv2; Ws = Ws2; fhi = fhi2; flo = flo2;
        ksteps = 1; idx = (b - w1B) * 256 + tid;
        if (idx >= 26 * 1 * 64 * 4) return;
    }
    int w = idx & 3;
    int lane = (idx >> 2) & 63;
    int tmp = idx >> 8;
    int kk = tmp % ksteps;
    int t = tmp / ksteps;
    int col = t * 16 + (lane & 15);
    int k0 = kk * 32 + ((lane >> 4) << 3) + (w << 1);
    const float* W; int ow, c;
    if (col < 128)      { W = Wq; ow = 128; c = col; }
    else if (col < 256) { W = Wk; ow = 128; c = col - 128; }
    else if (col < 384) { W = Wv; ow = 128; c = col - 256; }
    else                { W = Ws; ow = 32;  c = col - 384; }
    float v0 = W[(size_t)k0 * ow + c];
    float v1 = W[(size_t)(k0 + 1) * ow + c];
    unsigned short h0 = f2b(v0), h1 = f2b(v1);
    unsigned short l0 = f2b(v0 - b2f(h0)), l1 = f2b(v1 - b2f(h1));
    fhi[idx] = (unsigned)h0 | ((unsigned)h1 << 16);
    flo[idx] = (unsigned)l0 | ((unsigned)l1 << 16);
}

// ---------------- fused Q/K/V/skip projection via bf16 MFMA, split precision ----------------
// Persistent-B (NT=7, grid.y=4), zero-barrier row-tile loop, A software-pipelined one
// row-tile ahead. Outputs: q bf16, kv rows = [k 128 fp8 | v 128 fp8] (256B), sk f32.

template<int KSTEPS>
__global__ __launch_bounds__(1024) void qkvs_mfma(const unsigned short* __restrict__ Xc,
    int Cin, int N,
    const unsigned* __restrict__ fhi, const unsigned* __restrict__ flo,
    const float* __restrict__ bq, const float* __restrict__ bk,
    const float* __restrict__ bv, const float* __restrict__ bs,
    unsigned short* __restrict__ q, unsigned char* __restrict__ kvb,
    float* __restrict__ sk, int rtPer)
{
    constexpr int NT = 7;
    constexpr int NIDX = KSTEPS * NT * 2 * 64;      // 16B units
    __shared__ float4 ldsB[NIDX];

    int tid = threadIdx.x;
    int lane = tid & 63, wid = tid >> 6;
    int tbase = blockIdx.y * NT;

    for (int u = tid; u < NIDX; u += 1024) {
        int l = u & 63;
        int rest = u >> 6;
        int plane = rest & 1;
        int tt = (rest >> 1) % NT;
        int kk = (rest >> 1) / NT;
        if (tbase + tt < 26) {
            const unsigned* srcp = plane ? flo : fhi;
            size_t so = (((size_t)(tbase + tt) * KSTEPS + kk) * 64 + l) * 4;
            async_copy16(srcp + so, &ldsB[u - l]);
        }
    }
    __syncthreads();   // drains the async fills; only barrier in the kernel

    const int asub2 = ((lane >> 4) << 3) * 2;       // short-offset of this lane's group
    const int rowStride = 2 * Cin;
    int rtTotal = (N + 15) >> 4;
    int rtStart = blockIdx.x * rtPer;
    int rtEnd = rtStart + rtPer; if (rtEnd > rtTotal) rtEnd = rtTotal;

    auto loadA = [&](int rtX, bf16x8* dstA) {
        int row = rtX * 16 + (lane & 15);
        int rowc = row < N ? row : N - 1;
        const unsigned short* xp = Xc + (size_t)rowc * rowStride + asub2;
#pragma unroll
        for (int kk = 0; kk < KSTEPS; ++kk) {
            dstA[2 * kk]     = *(const bf16x8*)(xp + kk * 64);
            dstA[2 * kk + 1] = *(const bf16x8*)(xp + kk * 64 + 8);
        }
    };

    bf16x8 aCur[2 * KSTEPS];
    int rt0 = rtStart + wid;
    if (rt0 < rtEnd) loadA(rt0, aCur);

    for (int rt = rt0; rt < rtEnd; rt += 16) {
        bf16x8 aNxt[2 * KSTEPS];
        bool hasNext = (rt + 16) < rtEnd;
        if (hasNext) loadA(rt + 16, aNxt);      // prefetch next row-tile's A

        f32x4 acc[NT];
#pragma unroll
        for (int t = 0; t < NT; ++t) acc[t] = (f32x4){0.f, 0.f, 0.f, 0.f};

#pragma unroll
        for (int kk = 0; kk < KSTEPS; ++kk) {
            const float4* base = &ldsB[kk * NT * 2 * 64];
            bf16x8 ah = aCur[2 * kk], al = aCur[2 * kk + 1];
#pragma unroll
            for (int t = 0; t < NT; ++t) {
                bf16x8 bh = *(const bf16x8*)&base[(t * 2 + 0) * 64 + lane];
                bf16x8 bl = *(const bf16x8*)&base[(t * 2 + 1) * 64 + lane];
                acc[t] = mfma16(ah, bh, acc[t]);
                acc[t] = mfma16(al, bh, acc[t]);
                acc[t] = mfma16(ah, bl, acc[t]);
            }
        }

        // ---- store with bias; q bf16, k/v fp8 (kv row 256B), sk f32 ----
#pragma unroll
        for (int t = 0; t < NT; ++t) {
            int col = (tbase + t) * 16 + (lane & 15);
            if (col >= 416) continue;
            int sel; const float* bp; int c;
            if (col < 128)      { sel = 0; bp = bq; c = col; }
            else if (col < 256) { sel = 1; bp = bk; c = col - 128; }
            else if (col < 384) { sel = 2; bp = bv; c = col - 256; }
            else                { sel = 3; bp = bs; c = col - 384; }
            float bias = bp[c];
#pragma unroll
            for (int r = 0; r < 4; ++r) {
                int orow = rt * 16 + ((lane >> 4) << 2) + r;
                if (orow >= N) continue;
                float val = acc[t][r] + bias;
                if (sel == 0)      q[(size_t)orow * 128 + c] = f2b(val);
                else if (sel == 1) kvb[(size_t)orow * 256 + c] = f2e4m3(val);
                else if (sel == 2) kvb[(size_t)orow * 256 + 128 + c] = f2e4m3(val);
                else               sk[(size_t)orow * 32 + c] = val;
            }
        }

        if (hasNext) {
#pragma unroll
            for (int i = 0; i < 2 * KSTEPS; ++i) aCur[i] = aNxt[i];
        }
    }
}

// ---------------- per-node attention over CSR ----------------
// 32 threads per node; kv rows = [k 128 fp8 | v 128 fp8] (256B/src node), q bf16.
// fp8 decode via (bits<<20): exact incl. subnormals (f32 denormals preserved on gfx950 —
// verified by 3 rounds of fp8-v with unchanged absmax). 2^120 rescale folded into the
// logit constant (k) and softmax weight (v). No-max softmax, 4-way unroll.
// mode 0: f32 out; mode 1: interleaved hi|lo bf16 out.

__global__ __launch_bounds__(256) void attn_k(const unsigned short* __restrict__ q,
    const unsigned char* __restrict__ kv,
    const float* __restrict__ sk,
    const int* __restrict__ rowptr, const int* __restrict__ srcid,
    float* __restrict__ outF, unsigned short* __restrict__ outC, int mode, int N)
{
    int grp = threadIdx.x >> 5;
    int n = blockIdx.x * 8 + grp;
    if (n >= N) return;
    int l = threadIdx.x & 31;
    int s = l & 7;
    const float c2k = 0.25504233001306574f * 0x1p120f;   // 1/sqrt(32)/ln2 * 2^120

    ushort4 qr = *(const ushort4*)(q + (size_t)n * 128 + l * 4);
    float4 qv = make_float4(b2f(qr.x), b2f(qr.y), b2f(qr.z), b2f(qr.w));
    float4 acc = make_float4(0.f, 0.f, 0.f, 0.f);
    float lsum = 0.f;

    int e0 = rowptr[n], e1 = rowptr[n + 1];
    int e = e0;
    for (; e + 4 <= e1; e += 4) {
        int s0 = srcid[e], s1 = srcid[e + 1], s2 = srcid[e + 2], s3 = srcid[e + 3];
        const unsigned char* b0 = kv + (size_t)s0 * 256;
        const unsigned char* b1 = kv + (size_t)s1 * 256;
        const unsigned char* b2 = kv + (size_t)s2 * 256;
        const unsigned char* b3 = kv + (size_t)s3 * 256;
        unsigned kw0 = *(const unsigned*)(b0 + (l << 2));
        unsigned kw1 = *(const unsigned*)(b1 + (l << 2));
        unsigned kw2 = *(const unsigned*)(b2 + (l << 2));
        unsigned kw3 = *(const unsigned*)(b3 + (l << 2));
        unsigned vw0 = *(const unsigned*)(b0 + 128 + (l << 2));
        unsigned vw1 = *(const unsigned*)(b1 + 128 + (l << 2));
        unsigned vw2 = *(const unsigned*)(b2 + 128 + (l << 2));
        unsigned vw3 = *(const unsigned*)(b3 + 128 + (l << 2));

        float p0 = dot4_fp8(qv, kw0);
        float p1 = dot4_fp8(qv, kw1);
        float p2 = dot4_fp8(qv, kw2);
        float p3 = dot4_fp8(qv, kw3);
        p0 += __shfl_xor(p0, 1, 8); p0 += __shfl_xor(p0, 2, 8); p0 += __shfl_xor(p0, 4, 8);
        p1 += __shfl_xor(p1, 1, 8); p1 += __shfl_xor(p1, 2, 8); p1 += __shfl_xor(p1, 4, 8);
        p2 += __shfl_xor(p2, 1, 8); p2 += __shfl_xor(p2, 2, 8); p2 += __shfl_xor(p2, 4, 8);
        p3 += __shfl_xor(p3, 1, 8); p3 += __shfl_xor(p3, 2, 8); p3 += __shfl_xor(p3, 4, 8);
        float ex0 = exp2f(fminf(p0 * c2k, 86.f));
        float ex1 = exp2f(fminf(p1 * c2k, 86.f));
        float ex2 = exp2f(fminf(p2 * c2k, 86.f));
        float ex3 = exp2f(fminf(p3 * c2k, 86.f));
        lsum += (ex0 + ex1) + (ex2 + ex3);
        acc4_fp8(ex0 * 0x1p120f, vw0, acc);
        acc4_fp8(ex1 * 0x1p120f, vw1, acc);
        acc4_fp8(ex2 * 0x1p120f, vw2, acc);
        acc4_fp8(ex3 * 0x1p120f, vw3, acc);
    }
    for (; e < e1; ++e) {
        const unsigned char* b0 = kv + (size_t)srcid[e] * 256;
        unsigned kw0 = *(const unsigned*)(b0 + (l << 2));
        unsigned vw0 = *(const unsigned*)(b0 + 128 + (l << 2));
        float p0 = dot4_fp8(qv, kw0);
        p0 += __shfl_xor(p0, 1, 8); p0 += __shfl_xor(p0, 2, 8); p0 += __shfl_xor(p0, 4, 8);
        float ex0 = exp2f(fminf(p0 * c2k, 86.f));
        lsum += ex0;
        acc4_fp8(ex0 * 0x1p120f, vw0, acc);
    }

    float inv = 0.25f / fmaxf(lsum, 1e-16f);
    float rx = acc.x * inv, ry = acc.y * inv, rz = acc.z * inv, rw = acc.w * inv;
    rx += __shfl_xor(rx, 8, 32);  rx += __shfl_xor(rx, 16, 32);
    ry += __shfl_xor(ry, 8, 32);  ry += __shfl_xor(ry, 16, 32);
    rz += __shfl_xor(rz, 8, 32);  rz += __shfl_xor(rz, 16, 32);
    rw += __shfl_xor(rw, 8, 32);  rw += __shfl_xor(rw, 16, 32);

    if (l < 8) {
        const float* skp = sk + (size_t)n * 32 + s * 4;
        float o0 = fmaxf(rx + skp[0], 0.f), o1 = fmaxf(ry + skp[1], 0.f);
        float o2 = fmaxf(rz + skp[2], 0.f), o3 = fmaxf(rw + skp[3], 0.f);
        if (mode == 0) {
            *(float4*)(outF + (size_t)n * 32 + s * 4) = make_float4(o0, o1, o2, o3);
        } else {
            // interleaved hi|lo: row = 64 shorts, group g=s>>1, off=(s&1)*4
            ushort4 h, L;
            h.x = f2b(o0); L.x = f2b(o0 - b2f(h.x));
            h.y = f2b(o1); L.y = f2b(o1 - b2f(h.y));
            h.z = f2b(o2); L.z = f2b(o2 - b2f(h.z));
            h.w = f2b(o3); L.w = f2b(o3 - b2f(h.w));
            unsigned short* op = outC + (size_t)n * 64 + (s >> 1) * 16 + (s & 1) * 4;
            *(ushort4*)op       = h;
            *(ushort4*)(op + 8) = L;
        }
    }
}

// ---------------- global mean pool (batch is sorted) ----------------

__global__ __launch_bounds__(256) void pool_k(const float* __restrict__ h, const int* __restrict__ batch,
                                              float* __restrict__ out, int N)
{
    int g = blockIdx.x;
    int t = threadIdx.x;
    int lo = 0, hi = N;
    while (lo < hi) { int mid = (lo + hi) >> 1; if (batch[mid] < g) lo = mid + 1; else hi = mid; }
    int start = lo;
    lo = 0; hi = N;
    while (lo < hi) { int mid = (lo + hi) >> 1; if (batch[mid] < g + 1) lo = mid + 1; else hi = mid; }
    int end = lo;
    int c = t & 31, r0 = t >> 5;
    float s = 0.f;
    for (int r = start + r0; r < end; r += 8) s += h[(size_t)r * 32 + c];
    __shared__ float sh[256];
    sh[t] = s;
    __syncthreads();
    if (t < 32) {
        float tot = sh[t] + sh[t + 32] + sh[t + 64] + sh[t + 96]
                  + sh[t + 128] + sh[t + 160] + sh[t + 192] + sh[t + 224];
        float cnt = (float)(end - start);
        out[(size_t)g * 32 + t] = tot / fmaxf(cnt, 1.f);
    }
}

// ---------------- launch ----------------

extern "C" void kernel_launch(void* const* d_in, const int* in_sizes, int n_in,
                              void* d_out, int out_size, void* d_ws, size_t ws_size,
                              hipStream_t stream) {
    const float* x   = (const float*)d_in[0];
    const int* ei    = (const int*)d_in[1];
    const int* batch = (const int*)d_in[2];
    const float *Wq1 = (const float*)d_in[3],  *bq1 = (const float*)d_in[4];
    const float *Wk1 = (const float*)d_in[5],  *bk1 = (const float*)d_in[6];
    const float *Wv1 = (const float*)d_in[7],  *bv1 = (const float*)d_in[8];
    const float *Ws1 = (const float*)d_in[9],  *bs1 = (const float*)d_in[10];
    const float *Wq2 = (const float*)d_in[11], *bq2 = (const float*)d_in[12];
    const float *Wk2 = (const float*)d_in[13], *bk2 = (const float*)d_in[14];
    const float *Wv2 = (const float*)d_in[15], *bv2 = (const float*)d_in[16];
    const float *Ws2 = (const float*)d_in[17], *bs2 = (const float*)d_in[18];
    float* out = (float*)d_out;

    int N = in_sizes[0] / 128;
    int E = in_sizes[1] / 2;
    const int* src = ei;
    const int* dst = ei + E;

    char* ws = (char*)d_ws;
    size_t off = 0;
    auto alloc = [&](size_t bytes) -> void* {
        void* p = ws + off;
        off += (bytes + 255) & ~(size_t)255;
        return p;
    };
    int* deg      = (int*)alloc((size_t)N * 4);
    int* cnt      = (int*)alloc((size_t)N * 4);
    int* rowptr   = (int*)alloc(((size_t)N + 1) * 4);
    int* partials = (int*)alloc(4096);
    int* srcid    = (int*)alloc((size_t)E * 4);
    unsigned* fhi1 = (unsigned*)alloc(26 * 4 * 64 * 4 * 4);
    unsigned* flo1 = (unsigned*)alloc(26 * 4 * 64 * 4 * 4);
    unsigned* fhi2 = (unsigned*)alloc(26 * 1 * 64 * 4 * 4);
    unsigned* flo2 = (unsigned*)alloc(26 * 1 * 64 * 4 * 4);
    unsigned short* Xc  = (unsigned short*)alloc((size_t)N * 256 * 2);   // interleaved hi|lo
    unsigned short* q   = (unsigned short*)alloc((size_t)N * 128 * 2);
    unsigned char* kvb  = (unsigned char*)alloc((size_t)N * 256);
    float* sk     = (float*)alloc((size_t)N * 32 * 4);
    unsigned short* h1c = (unsigned short*)alloc((size_t)N * 64 * 2);    // interleaved hi|lo
    float* h2     = (float*)alloc((size_t)N * 32 * 4);

    hipMemsetAsync(deg, 0, (size_t)N * 4, stream);
    hipMemsetAsync(cnt, 0, (size_t)N * 4, stream);

    int histB = (E + 255) / 256;
    int ngrp = N * 16;                       // N*128/8 groups
    int cvtB = (ngrp + 255) / 256;
    int w1B = (26 * 4 * 64 * 4 + 255) / 256;
    int w2B = (26 * 1 * 64 * 4 + 255) / 256;
    prep_k<<<histB + cvtB + w1B + w2B, 256, 0, stream>>>(
        dst, deg, E, histB,
        x, Xc, ngrp, cvtB,
        Wq1, Wk1, Wv1, Ws1, fhi1, flo1, w1B,
        Wq2, Wk2, Wv2, Ws2, fhi2, flo2);

    int nch = (N + 1023) / 1024;
    scanA_k<<<nch, 256, 0, stream>>>(deg, rowptr, partials, N);
    scanB_k<<<1, 64, 0, stream>>>(partials, nch);
    addoff_k<<<nch, 256, 0, stream>>>(rowptr, partials, N, nch);
    scatter_k<<<(E + 255) / 256, 256, 0, stream>>>(src, dst, rowptr, cnt, srcid, E);

    int rtTotal = (N + 15) / 16;
    int rtPer = (rtTotal + 127) / 128;
    dim3 gq(128, 4);
    qkvs_mfma<4><<<gq, 1024, 0, stream>>>(Xc, 128, N, fhi1, flo1,
        bq1, bk1, bv1, bs1, q, kvb, sk, rtPer);
    attn_k<<<(N + 7) / 8, 256, 0, stream>>>(q, kvb, sk, rowptr, srcid,
        nullptr, h1c, 1, N);
    qkvs_mfma<1><<<gq, 1024, 0, stream>>>(h1c, 32, N, fhi2, flo2,
        bq2, bk2, bv2, bs2, q, kvb, sk, rtPer);
    attn_k<<<(N + 7) / 8, 256, 0, stream>>>(q, kvb, sk, rowptr, srcid,
        h2, nullptr, 0, N);
    pool_k<<<512, 256, 0, stream>>>(h2, batch, out, N);
}

// Round 20
// 517.831 us; speedup vs baseline: 1.1552x; 1.1552x over previous
//
#include <hip/hip_runtime.h>
#include <math.h>

typedef __attribute__((ext_vector_type(8))) short bf16x8;
typedef __attribute__((ext_vector_type(4))) float f32x4;
typedef __attribute__((ext_vector_type(2))) float f32x2;

__device__ __forceinline__ float b2f(unsigned short u) {
    union { unsigned u32; float f; } x; x.u32 = (unsigned)u << 16; return x.f;
}
__device__ __forceinline__ unsigned short f2b(float f) {
    union { float f; unsigned u32; } x; x.f = f;
    unsigned u = x.u32;
    unsigned r = (u + 0x7fffu + ((u >> 16) & 1u)) >> 16;   // RNE
    return (unsigned short)r;
}

// f32 -> OCP e4m3fn, RNE, clamp to +-448, subnormals exact.
__device__ __forceinline__ unsigned char f2e4m3(float f) {
    union { float f; unsigned u; } x; x.f = f;
    unsigned s = (x.u >> 24) & 0x80;
    x.u &= 0x7fffffff;
    if (!(x.f == x.f)) return (unsigned char)(s | 0x7e);
    if (x.f >= 448.f) return (unsigned char)(s | 0x7e);
    if (x.f < 0.015625f) {                       // subnormal: m * 2^-9, RNE
        int m = (int)rintf(x.f * 512.f);
        if (m >= 8) return (unsigned char)(s | 0x08);
        return (unsigned char)(s | (unsigned)m);
    }
    unsigned exp = x.u >> 23;
    unsigned mant = x.u & 0x7fffff;
    unsigned m3 = mant >> 20;
    unsigned rb = (mant >> 19) & 1u;
    unsigned sticky = (mant & 0x7ffffu) ? 1u : 0u;
    m3 += rb & (sticky | (m3 & 1u));
    if (m3 == 8) { m3 = 0; exp++; }
    unsigned e4 = exp - 120;                     // bias 7
    if (e4 >= 15 && m3 > 6) { e4 = 15; m3 = 6; } // stay <= 448
    return (unsigned char)(s | (e4 << 3) | m3);
}

// hardware decode: 4 packed OCP-e4m3 bytes -> 4 f32 (2 x v_cvt_pk_f32_fp8)
__device__ __forceinline__ float4 cvt4_fp8(unsigned w) {
    f32x2 lo = __builtin_amdgcn_cvt_pk_f32_fp8((int)w, false);
    f32x2 hi = __builtin_amdgcn_cvt_pk_f32_fp8((int)w, true);
    return make_float4(lo[0], lo[1], hi[0], hi[1]);
}

__device__ __forceinline__ f32x4 mfma16(bf16x8 a, bf16x8 b, f32x4 c) {
    return __builtin_amdgcn_mfma_f32_16x16x32_bf16(a, b, c, 0, 0, 0);
}

// async global->LDS, 16B per lane: lds dest = uniform base + lane*16, global src per-lane.
__device__ __forceinline__ void async_copy16(const unsigned* g, void* l) {
    __builtin_amdgcn_global_load_lds(
        (const __attribute__((address_space(1))) unsigned*)g,
        (__attribute__((address_space(3))) unsigned*)l, 16, 0, 0);
}

// ---------------- CSR scan pieces ----------------

__global__ __launch_bounds__(256) void scanA_k(const int* __restrict__ deg, int* __restrict__ rowptr,
                                               int* __restrict__ partials, int N) {
    __shared__ int sh[256];
    int t = threadIdx.x;
    int base = blockIdx.x * 1024 + t * 4;
    int v0 = 0, v1 = 0, v2 = 0, v3 = 0;
    if (base + 0 < N) v0 = deg[base + 0];
    if (base + 1 < N) v1 = deg[base + 1];
    if (base + 2 < N) v2 = deg[base + 2];
    if (base + 3 < N) v3 = deg[base + 3];
    sh[t] = v0 + v1 + v2 + v3;
    __syncthreads();
    for (int off = 1; off < 256; off <<= 1) {
        int add = (t >= off) ? sh[t - off] : 0;
        __syncthreads();
        sh[t] += add;
        __syncthreads();
    }
    int run = (t > 0) ? sh[t - 1] : 0;
    if (base + 0 < N) rowptr[base + 0] = run; run += v0;
    if (base + 1 < N) rowptr[base + 1] = run; run += v1;
    if (base + 2 < N) rowptr[base + 2] = run; run += v2;
    if (base + 3 < N) rowptr[base + 3] = run;
    if (t == 255) partials[blockIdx.x] = sh[255];
}

__global__ void scanB_k(int* partials, int nch) {
    if (threadIdx.x == 0 && blockIdx.x == 0) {
        int run = 0;
        for (int i = 0; i < nch; ++i) { int x = partials[i]; partials[i] = run; run += x; }
        partials[nch] = run;
    }
}

__global__ __launch_bounds__(256) void addoff_k(int* __restrict__ rowptr, const int* __restrict__ partials,
                                                int N, int nch) {
    int t = threadIdx.x;
    int off = partials[blockIdx.x];
    int base = blockIdx.x * 1024;
    for (int i = 0; i < 4; ++i) {
        int idx = base + t + i * 256;
        if (idx < N) rowptr[idx] += off;
    }
    if (blockIdx.x == 0 && t == 0) rowptr[N] = partials[nch];
}

__global__ __launch_bounds__(256) void scatter_k(const int* __restrict__ src, const int* __restrict__ dst,
                                                 const int* __restrict__ rowptr, int* __restrict__ cnt,
                                                 int* __restrict__ srcid, int E) {
    int e = blockIdx.x * 256 + threadIdx.x;
    if (e < E) {
        int d = dst[e];
        int pos = rowptr[d] + atomicAdd(&cnt[d], 1);
        srcid[pos] = src[e];
    }
}

// ---------------- merged prologue: hist + cvt(interleaved) + wprep x2 ----------------
// X interleaved layout: row = 2*Cin shorts; 8-col group g: hi8 at [g*16, g*16+8), lo8 at +8.

__global__ __launch_bounds__(256) void prep_k(
    const int* __restrict__ dst, int* __restrict__ deg, int E, int histB,
    const float* __restrict__ x, unsigned short* __restrict__ Xc, int ngrp, int cvtB,
    const float* __restrict__ Wq1, const float* __restrict__ Wk1,
    const float* __restrict__ Wv1, const float* __restrict__ Ws1,
    unsigned* __restrict__ fhi1, unsigned* __restrict__ flo1, int w1B,
    const float* __restrict__ Wq2, const float* __restrict__ Wk2,
    const float* __restrict__ Wv2, const float* __restrict__ Ws2,
    unsigned* __restrict__ fhi2, unsigned* __restrict__ flo2)
{
    int b = blockIdx.x;
    int tid = threadIdx.x;
    if (b < histB) {
        int e = b * 256 + tid;
        if (e < E) atomicAdd(&deg[dst[e]], 1);
        return;
    }
    b -= histB;
    if (b < cvtB) {
        int gi = b * 256 + tid;   // group of 8 f32 -> hi8|lo8 (32B contiguous)
        if (gi < ngrp) {
            const float* xp = x + (size_t)gi * 8;
            float4 a0 = *(const float4*)xp;
            float4 a1 = *(const float4*)(xp + 4);
            unsigned short* op = Xc + (size_t)gi * 16;
            ushort4 h0, h1, L0, L1;
            h0.x = f2b(a0.x); L0.x = f2b(a0.x - b2f(h0.x));
            h0.y = f2b(a0.y); L0.y = f2b(a0.y - b2f(h0.y));
            h0.z = f2b(a0.z); L0.z = f2b(a0.z - b2f(h0.z));
            h0.w = f2b(a0.w); L0.w = f2b(a0.w - b2f(h0.w));
            h1.x = f2b(a1.x); L1.x = f2b(a1.x - b2f(h1.x));
            h1.y = f2b(a1.y); L1.y = f2b(a1.y - b2f(h1.y));
            h1.z = f2b(a1.z); L1.z = f2b(a1.z - b2f(h1.z));
            h1.w = f2b(a1.w); L1.w = f2b(a1.w - b2f(h1.w));
            *(ushort4*)(op)      = h0;
            *(ushort4*)(op + 4)  = h1;
            *(ushort4*)(op + 8)  = L0;
            *(ushort4*)(op + 12) = L1;
        }
        return;
    }
    b -= cvtB;
    const float *Wq, *Wk, *Wv, *Ws; unsigned *fhi, *flo; int ksteps, idx;
    if (b < w1B) {
        Wq = Wq1; Wk = Wk1; Wv = Wv1; Ws = Ws1; fhi = fhi1; flo = flo1;
        ksteps = 4; idx = b * 256 + tid;
        if (idx >= 26 * 4 * 64 * 4) return;
    } else {
        Wq = Wq2; Wk = Wk2; Wv = Wv2; Ws = Ws2; fhi = fhi2; flo = flo2;
        ksteps = 1; idx = (b - w1B) * 256 + tid;
        if (idx >= 26 * 1 * 64 * 4) return;
    }
    int w = idx & 3;
    int lane = (idx >> 2) & 63;
    int tmp = idx >> 8;
    int kk = tmp % ksteps;
    int t = tmp / ksteps;
    int col = t * 16 + (lane & 15);
    int k0 = kk * 32 + ((lane >> 4) << 3) + (w << 1);
    const float* W; int ow, c;
    if (col < 128)      { W = Wq; ow = 128; c = col; }
    else if (col < 256) { W = Wk; ow = 128; c = col - 128; }
    else if (col < 384) { W = Wv; ow = 128; c = col - 256; }
    else                { W = Ws; ow = 32;  c = col - 384; }
    float v0 = W[(size_t)k0 * ow + c];
    float v1 = W[(size_t)(k0 + 1) * ow + c];
    unsigned short h0 = f2b(v0), h1 = f2b(v1);
    unsigned short l0 = f2b(v0 - b2f(h0)), l1 = f2b(v1 - b2f(h1));
    fhi[idx] = (unsigned)h0 | ((unsigned)h1 << 16);
    flo[idx] = (unsigned)l0 | ((unsigned)l1 << 16);
}

// ---------------- fused Q/K/V/skip projection via bf16 MFMA, split precision ----------------
// Persistent-B (NT=7, grid.y=4), zero-barrier row-tile loop, A software-pipelined one
// row-tile ahead. Outputs: q bf16, kv rows = [k 128 fp8 | v 128 fp8] (256B), sk f32.

template<int KSTEPS>
__global__ __launch_bounds__(1024) void qkvs_mfma(const unsigned short* __restrict__ Xc,
    int Cin, int N,
    const unsigned* __restrict__ fhi, const unsigned* __restrict__ flo,
    const float* __restrict__ bq, const float* __restrict__ bk,
    const float* __restrict__ bv, const float* __restrict__ bs,
    unsigned short* __restrict__ q, unsigned char* __restrict__ kvb,
    float* __restrict__ sk, int rtPer)
{
    constexpr int NT = 7;
    constexpr int NIDX = KSTEPS * NT * 2 * 64;      // 16B units
    __shared__ float4 ldsB[NIDX];

    int tid = threadIdx.x;
    int lane = tid & 63, wid = tid >> 6;
    int tbase = blockIdx.y * NT;

    for (int u = tid; u < NIDX; u += 1024) {
        int l = u & 63;
        int rest = u >> 6;
        int plane = rest & 1;
        int tt = (rest >> 1) % NT;
        int kk = (rest >> 1) / NT;
        if (tbase + tt < 26) {
            const unsigned* srcp = plane ? flo : fhi;
            size_t so = (((size_t)(tbase + tt) * KSTEPS + kk) * 64 + l) * 4;
            async_copy16(srcp + so, &ldsB[u - l]);
        }
    }
    __syncthreads();   // drains the async fills; only barrier in the kernel

    const int asub2 = ((lane >> 4) << 3) * 2;       // short-offset of this lane's group
    const int rowStride = 2 * Cin;
    int rtTotal = (N + 15) >> 4;
    int rtStart = blockIdx.x * rtPer;
    int rtEnd = rtStart + rtPer; if (rtEnd > rtTotal) rtEnd = rtTotal;

    auto loadA = [&](int rtX, bf16x8* dstA) {
        int row = rtX * 16 + (lane & 15);
        int rowc = row < N ? row : N - 1;
        const unsigned short* xp = Xc + (size_t)rowc * rowStride + asub2;
#pragma unroll
        for (int kk = 0; kk < KSTEPS; ++kk) {
            dstA[2 * kk]     = *(const bf16x8*)(xp + kk * 64);
            dstA[2 * kk + 1] = *(const bf16x8*)(xp + kk * 64 + 8);
        }
    };

    bf16x8 aCur[2 * KSTEPS];
    int rt0 = rtStart + wid;
    if (rt0 < rtEnd) loadA(rt0, aCur);

    for (int rt = rt0; rt < rtEnd; rt += 16) {
        bf16x8 aNxt[2 * KSTEPS];
        bool hasNext = (rt + 16) < rtEnd;
        if (hasNext) loadA(rt + 16, aNxt);      // prefetch next row-tile's A

        f32x4 acc[NT];
#pragma unroll
        for (int t = 0; t < NT; ++t) acc[t] = (f32x4){0.f, 0.f, 0.f, 0.f};

#pragma unroll
        for (int kk = 0; kk < KSTEPS; ++kk) {
            const float4* base = &ldsB[kk * NT * 2 * 64];
            bf16x8 ah = aCur[2 * kk], al = aCur[2 * kk + 1];
#pragma unroll
            for (int t = 0; t < NT; ++t) {
                bf16x8 bh = *(const bf16x8*)&base[(t * 2 + 0) * 64 + lane];
                bf16x8 bl = *(const bf16x8*)&base[(t * 2 + 1) * 64 + lane];
                acc[t] = mfma16(ah, bh, acc[t]);
                acc[t] = mfma16(al, bh, acc[t]);
                acc[t] = mfma16(ah, bl, acc[t]);
            }
        }

        // ---- store with bias; q bf16, k/v fp8 (kv row 256B), sk f32 ----
#pragma unroll
        for (int t = 0; t < NT; ++t) {
            int col = (tbase + t) * 16 + (lane & 15);
            if (col >= 416) continue;
            int sel; const float* bp; int c;
            if (col < 128)      { sel = 0; bp = bq; c = col; }
            else if (col < 256) { sel = 1; bp = bk; c = col - 128; }
            else if (col < 384) { sel = 2; bp = bv; c = col - 256; }
            else                { sel = 3; bp = bs; c = col - 384; }
            float bias = bp[c];
#pragma unroll
            for (int r = 0; r < 4; ++r) {
                int orow = rt * 16 + ((lane >> 4) << 2) + r;
                if (orow >= N) continue;
                float val = acc[t][r] + bias;
                if (sel == 0)      q[(size_t)orow * 128 + c] = f2b(val);
                else if (sel == 1) kvb[(size_t)orow * 256 + c] = f2e4m3(val);
                else if (sel == 2) kvb[(size_t)orow * 256 + 128 + c] = f2e4m3(val);
                else               sk[(size_t)orow * 32 + c] = val;
            }
        }

        if (hasNext) {
#pragma unroll
            for (int i = 0; i < 2 * KSTEPS; ++i) aCur[i] = aNxt[i];
        }
    }
}

// ---------------- per-node attention over CSR ----------------
// 32 threads per node; kv rows = [k 128 fp8 | v 128 fp8] (256B/src node), q bf16.
// fp8 decode via HARDWARE v_cvt_pk_f32_fp8 (OCP e4m3, matches encoder): 2 ops per
// 4 values vs ~20 int-ops for the R19 software decode (which made attn 97% VALU-bound).
// No-max softmax, exp2 folded scale, 4-way unroll.
// mode 0: f32 out; mode 1: interleaved hi|lo bf16 out.

__global__ __launch_bounds__(256) void attn_k(const unsigned short* __restrict__ q,
    const unsigned char* __restrict__ kv,
    const float* __restrict__ sk,
    const int* __restrict__ rowptr, const int* __restrict__ srcid,
    float* __restrict__ outF, unsigned short* __restrict__ outC, int mode, int N)
{
    int grp = threadIdx.x >> 5;
    int n = blockIdx.x * 8 + grp;
    if (n >= N) return;
    int l = threadIdx.x & 31;
    int s = l & 7;
    const float c2 = 0.25504233001306574f;   // 1/sqrt(32) * 1/ln(2)

    ushort4 qr = *(const ushort4*)(q + (size_t)n * 128 + l * 4);
    float4 qv = make_float4(b2f(qr.x), b2f(qr.y), b2f(qr.z), b2f(qr.w));
    float4 acc = make_float4(0.f, 0.f, 0.f, 0.f);
    float lsum = 0.f;

    int e0 = rowptr[n], e1 = rowptr[n + 1];
    int e = e0;
    for (; e + 4 <= e1; e += 4) {
        int s0 = srcid[e], s1 = srcid[e + 1], s2 = srcid[e + 2], s3 = srcid[e + 3];
        const unsigned char* b0 = kv + (size_t)s0 * 256;
        const unsigned char* b1 = kv + (size_t)s1 * 256;
        const unsigned char* b2 = kv + (size_t)s2 * 256;
        const unsigned char* b3 = kv + (size_t)s3 * 256;
        unsigned kw0 = *(const unsigned*)(b0 + (l << 2));
        unsigned kw1 = *(const unsigned*)(b1 + (l << 2));
        unsigned kw2 = *(const unsigned*)(b2 + (l << 2));
        unsigned kw3 = *(const unsigned*)(b3 + (l << 2));
        unsigned vw0 = *(const unsigned*)(b0 + 128 + (l << 2));
        unsigned vw1 = *(const unsigned*)(b1 + 128 + (l << 2));
        unsigned vw2 = *(const unsigned*)(b2 + 128 + (l << 2));
        unsigned vw3 = *(const unsigned*)(b3 + 128 + (l << 2));

        float4 k40 = cvt4_fp8(kw0);
        float4 k41 = cvt4_fp8(kw1);
        float4 k42 = cvt4_fp8(kw2);
        float4 k43 = cvt4_fp8(kw3);
        float p0 = qv.x * k40.x + qv.y * k40.y + qv.z * k40.z + qv.w * k40.w;
        float p1 = qv.x * k41.x + qv.y * k41.y + qv.z * k41.z + qv.w * k41.w;
        float p2 = qv.x * k42.x + qv.y * k42.y + qv.z * k42.z + qv.w * k42.w;
        float p3 = qv.x * k43.x + qv.y * k43.y + qv.z * k43.z + qv.w * k43.w;
        p0 += __shfl_xor(p0, 1, 8); p0 += __shfl_xor(p0, 2, 8); p0 += __shfl_xor(p0, 4, 8);
        p1 += __shfl_xor(p1, 1, 8); p1 += __shfl_xor(p1, 2, 8); p1 += __shfl_xor(p1, 4, 8);
        p2 += __shfl_xor(p2, 1, 8); p2 += __shfl_xor(p2, 2, 8); p2 += __shfl_xor(p2, 4, 8);
        p3 += __shfl_xor(p3, 1, 8); p3 += __shfl_xor(p3, 2, 8); p3 += __shfl_xor(p3, 4, 8);
        float ex0 = exp2f(fminf(p0 * c2, 86.f));
        float ex1 = exp2f(fminf(p1 * c2, 86.f));
        float ex2 = exp2f(fminf(p2 * c2, 86.f));
        float ex3 = exp2f(fminf(p3 * c2, 86.f));
        lsum += (ex0 + ex1) + (ex2 + ex3);
        float4 v40 = cvt4_fp8(vw0);
        float4 v41 = cvt4_fp8(vw1);
        float4 v42 = cvt4_fp8(vw2);
        float4 v43 = cvt4_fp8(vw3);
        acc.x += ex0 * v40.x + ex1 * v41.x + ex2 * v42.x + ex3 * v43.x;
        acc.y += ex0 * v40.y + ex1 * v41.y + ex2 * v42.y + ex3 * v43.y;
        acc.z += ex0 * v40.z + ex1 * v41.z + ex2 * v42.z + ex3 * v43.z;
        acc.w += ex0 * v40.w + ex1 * v41.w + ex2 * v42.w + ex3 * v43.w;
    }
    for (; e < e1; ++e) {
        const unsigned char* b0 = kv + (size_t)srcid[e] * 256;
        unsigned kw0 = *(const unsigned*)(b0 + (l << 2));
        unsigned vw0 = *(const unsigned*)(b0 + 128 + (l << 2));
        float4 k40 = cvt4_fp8(kw0);
        float p0 = qv.x * k40.x + qv.y * k40.y + qv.z * k40.z + qv.w * k40.w;
        p0 += __shfl_xor(p0, 1, 8); p0 += __shfl_xor(p0, 2, 8); p0 += __shfl_xor(p0, 4, 8);
        float ex0 = exp2f(fminf(p0 * c2, 86.f));
        lsum += ex0;
        float4 v40 = cvt4_fp8(vw0);
        acc.x += ex0 * v40.x;
        acc.y += ex0 * v40.y;
        acc.z += ex0 * v40.z;
        acc.w += ex0 * v40.w;
    }

    float inv = 0.25f / fmaxf(lsum, 1e-16f);
    float rx = acc.x * inv, ry = acc.y * inv, rz = acc.z * inv, rw = acc.w * inv;
    rx += __shfl_xor(rx, 8, 32);  rx += __shfl_xor(rx, 16, 32);
    ry += __shfl_xor(ry, 8, 32);  ry += __shfl_xor(ry, 16, 32);
    rz += __shfl_xor(rz, 8, 32);  rz += __shfl_xor(rz, 16, 32);
    rw += __shfl_xor(rw, 8, 32);  rw += __shfl_xor(rw, 16, 32);

    if (l < 8) {
        const float* skp = sk + (size_t)n * 32 + s * 4;
        float o0 = fmaxf(rx + skp[0], 0.f), o1 = fmaxf(ry + skp[1], 0.f);
        float o2 = fmaxf(rz + skp[2], 0.f), o3 = fmaxf(rw + skp[3], 0.f);
        if (mode == 0) {
            *(float4*)(outF + (size_t)n * 32 + s * 4) = make_float4(o0, o1, o2, o3);
        } else {
            // interleaved hi|lo: row = 64 shorts, group g=s>>1, off=(s&1)*4
            ushort4 h, L;
            h.x = f2b(o0); L.x = f2b(o0 - b2f(h.x));
            h.y = f2b(o1); L.y = f2b(o1 - b2f(h.y));
            h.z = f2b(o2); L.z = f2b(o2 - b2f(h.z));
            h.w = f2b(o3); L.w = f2b(o3 - b2f(h.w));
            unsigned short* op = outC + (size_t)n * 64 + (s >> 1) * 16 + (s & 1) * 4;
            *(ushort4*)op       = h;
            *(ushort4*)(op + 8) = L;
        }
    }
}

// ---------------- global mean pool (batch is sorted) ----------------

__global__ __launch_bounds__(256) void pool_k(const float* __restrict__ h, const int* __restrict__ batch,
                                              float* __restrict__ out, int N)
{
    int g = blockIdx.x;
    int t = threadIdx.x;
    int lo = 0, hi = N;
    while (lo < hi) { int mid = (lo + hi) >> 1; if (batch[mid] < g) lo = mid + 1; else hi = mid; }
    int start = lo;
    lo = 0; hi = N;
    while (lo < hi) { int mid = (lo + hi) >> 1; if (batch[mid] < g + 1) lo = mid + 1; else hi = mid; }
    int end = lo;
    int c = t & 31, r0 = t >> 5;
    float s = 0.f;
    for (int r = start + r0; r < end; r += 8) s += h[(size_t)r * 32 + c];
    __shared__ float sh[256];
    sh[t] = s;
    __syncthreads();
    if (t < 32) {
        float tot = sh[t] + sh[t + 32] + sh[t + 64] + sh[t + 96]
                  + sh[t + 128] + sh[t + 160] + sh[t + 192] + sh[t + 224];
        float cnt = (float)(end - start);
        out[(size_t)g * 32 + t] = tot / fmaxf(cnt, 1.f);
    }
}

// ---------------- launch ----------------

extern "C" void kernel_launch(void* const* d_in, const int* in_sizes, int n_in,
                              void* d_out, int out_size, void* d_ws, size_t ws_size,
                              hipStream_t stream) {
    const float* x   = (const float*)d_in[0];
    const int* ei    = (const int*)d_in[1];
    const int* batch = (const int*)d_in[2];
    const float *Wq1 = (const float*)d_in[3],  *bq1 = (const float*)d_in[4];
    const float *Wk1 = (const float*)d_in[5],  *bk1 = (const float*)d_in[6];
    const float *Wv1 = (const float*)d_in[7],  *bv1 = (const float*)d_in[8];
    const float *Ws1 = (const float*)d_in[9],  *bs1 = (const float*)d_in[10];
    const float *Wq2 = (const float*)d_in[11], *bq2 = (const float*)d_in[12];
    const float *Wk2 = (const float*)d_in[13], *bk2 = (const float*)d_in[14];
    const float *Wv2 = (const float*)d_in[15], *bv2 = (const float*)d_in[16];
    const float *Ws2 = (const float*)d_in[17], *bs2 = (const float*)d_in[18];
    float* out = (float*)d_out;

    int N = in_sizes[0] / 128;
    int E = in_sizes[1] / 2;
    const int* src = ei;
    const int* dst = ei + E;

    char* ws = (char*)d_ws;
    size_t off = 0;
    auto alloc = [&](size_t bytes) -> void* {
        void* p = ws + off;
        off += (bytes + 255) & ~(size_t)255;
        return p;
    };
    int* deg      = (int*)alloc((size_t)N * 4);
    int* cnt      = (int*)alloc((size_t)N * 4);
    int* rowptr   = (int*)alloc(((size_t)N + 1) * 4);
    int* partials = (int*)alloc(4096);
    int* srcid    = (int*)alloc((size_t)E * 4);
    unsigned* fhi1 = (unsigned*)alloc(26 * 4 * 64 * 4 * 4);
    unsigned* flo1 = (unsigned*)alloc(26 * 4 * 64 * 4 * 4);
    unsigned* fhi2 = (unsigned*)alloc(26 * 1 * 64 * 4 * 4);
    unsigned* flo2 = (unsigned*)alloc(26 * 1 * 64 * 4 * 4);
    unsigned short* Xc  = (unsigned short*)alloc((size_t)N * 256 * 2);   // interleaved hi|lo
    unsigned short* q   = (unsigned short*)alloc((size_t)N * 128 * 2);
    unsigned char* kvb  = (unsigned char*)alloc((size_t)N * 256);
    float* sk     = (float*)alloc((size_t)N * 32 * 4);
    unsigned short* h1c = (unsigned short*)alloc((size_t)N * 64 * 2);    // interleaved hi|lo
    float* h2     = (float*)alloc((size_t)N * 32 * 4);

    hipMemsetAsync(deg, 0, (size_t)N * 4, stream);
    hipMemsetAsync(cnt, 0, (size_t)N * 4, stream);

    int histB = (E + 255) / 256;
    int ngrp = N * 16;                       // N*128/8 groups
    int cvtB = (ngrp + 255) / 256;
    int w1B = (26 * 4 * 64 * 4 + 255) / 256;
    int w2B = (26 * 1 * 64 * 4 + 255) / 256;
    prep_k<<<histB + cvtB + w1B + w2B, 256, 0, stream>>>(
        dst, deg, E, histB,
        x, Xc, ngrp, cvtB,
        Wq1, Wk1, Wv1, Ws1, fhi1, flo1, w1B,
        Wq2, Wk2, Wv2, Ws2, fhi2, flo2);

    int nch = (N + 1023) / 1024;
    scanA_k<<<nch, 256, 0, stream>>>(deg, rowptr, partials, N);
    scanB_k<<<1, 64, 0, stream>>>(partials, nch);
    addoff_k<<<nch, 256, 0, stream>>>(rowptr, partials, N, nch);
    scatter_k<<<(E + 255) / 256, 256, 0, stream>>>(src, dst, rowptr, cnt, srcid, E);

    int rtTotal = (N + 15) / 16;
    int rtPer = (rtTotal + 127) / 128;
    dim3 gq(128, 4);
    qkvs_mfma<4><<<gq, 1024, 0, stream>>>(Xc, 128, N, fhi1, flo1,
        bq1, bk1, bv1, bs1, q, kvb, sk, rtPer);
    attn_k<<<(N + 7) / 8, 256, 0, stream>>>(q, kvb, sk, rowptr, srcid,
        nullptr, h1c, 1, N);
    qkvs_mfma<1><<<gq, 1024, 0, stream>>>(h1c, 32, N, fhi2, flo2,
        bq2, bk2, bv2, bs2, q, kvb, sk, rtPer);
    attn_k<<<(N + 7) / 8, 256, 0, stream>>>(q, kvb, sk, rowptr, srcid,
        h2, nullptr, 0, N);
    pool_k<<<512, 256, 0, stream>>>(h2, batch, out, N);
}

// Round 21
// 490.240 us; speedup vs baseline: 1.2203x; 1.0563x over previous
//
#include <hip/hip_runtime.h>
#include <math.h>

typedef __attribute__((ext_vector_type(8))) short bf16x8;
typedef __attribute__((ext_vector_type(4))) float f32x4;
typedef __attribute__((ext_vector_type(2))) float f32x2;

__device__ __forceinline__ float b2f(unsigned short u) {
    union { unsigned u32; float f; } x; x.u32 = (unsigned)u << 16; return x.f;
}
__device__ __forceinline__ unsigned short f2b(float f) {
    union { float f; unsigned u32; } x; x.f = f;
    unsigned u = x.u32;
    unsigned r = (u + 0x7fffu + ((u >> 16) & 1u)) >> 16;   // RNE
    return (unsigned short)r;
}

// f32 -> OCP e4m3fn, RNE, clamp to +-448, subnormals exact.
__device__ __forceinline__ unsigned char f2e4m3(float f) {
    union { float f; unsigned u; } x; x.f = f;
    unsigned s = (x.u >> 24) & 0x80;
    x.u &= 0x7fffffff;
    if (!(x.f == x.f)) return (unsigned char)(s | 0x7e);
    if (x.f >= 448.f) return (unsigned char)(s | 0x7e);
    if (x.f < 0.015625f) {                       // subnormal: m * 2^-9, RNE
        int m = (int)rintf(x.f * 512.f);
        if (m >= 8) return (unsigned char)(s | 0x08);
        return (unsigned char)(s | (unsigned)m);
    }
    unsigned exp = x.u >> 23;
    unsigned mant = x.u & 0x7fffff;
    unsigned m3 = mant >> 20;
    unsigned rb = (mant >> 19) & 1u;
    unsigned sticky = (mant & 0x7ffffu) ? 1u : 0u;
    m3 += rb & (sticky | (m3 & 1u));
    if (m3 == 8) { m3 = 0; exp++; }
    unsigned e4 = exp - 120;                     // bias 7
    if (e4 >= 15 && m3 > 6) { e4 = 15; m3 = 6; } // stay <= 448
    return (unsigned char)(s | (e4 << 3) | m3);
}

// hardware decode: 4 packed OCP-e4m3 bytes -> 4 f32 (2 x v_cvt_pk_f32_fp8)
__device__ __forceinline__ float4 cvt4_fp8(unsigned w) {
    f32x2 lo = __builtin_amdgcn_cvt_pk_f32_fp8((int)w, false);
    f32x2 hi = __builtin_amdgcn_cvt_pk_f32_fp8((int)w, true);
    return make_float4(lo[0], lo[1], hi[0], hi[1]);
}

__device__ __forceinline__ f32x4 mfma16(bf16x8 a, bf16x8 b, f32x4 c) {
    return __builtin_amdgcn_mfma_f32_16x16x32_bf16(a, b, c, 0, 0, 0);
}

// async global->LDS, 16B per lane: lds dest = uniform base + lane*16, global src per-lane.
__device__ __forceinline__ void async_copy16(const unsigned* g, void* l) {
    __builtin_amdgcn_global_load_lds(
        (const __attribute__((address_space(1))) unsigned*)g,
        (__attribute__((address_space(3))) unsigned*)l, 16, 0, 0);
}

// ---------------- CSR scan pieces ----------------

__global__ __launch_bounds__(256) void scanA_k(const int* __restrict__ deg, int* __restrict__ rowptr,
                                               int* __restrict__ partials, int N) {
    __shared__ int sh[256];
    int t = threadIdx.x;
    int base = blockIdx.x * 1024 + t * 4;
    int v0 = 0, v1 = 0, v2 = 0, v3 = 0;
    if (base + 0 < N) v0 = deg[base + 0];
    if (base + 1 < N) v1 = deg[base + 1];
    if (base + 2 < N) v2 = deg[base + 2];
    if (base + 3 < N) v3 = deg[base + 3];
    sh[t] = v0 + v1 + v2 + v3;
    __syncthreads();
    for (int off = 1; off < 256; off <<= 1) {
        int add = (t >= off) ? sh[t - off] : 0;
        __syncthreads();
        sh[t] += add;
        __syncthreads();
    }
    int run = (t > 0) ? sh[t - 1] : 0;
    if (base + 0 < N) rowptr[base + 0] = run; run += v0;
    if (base + 1 < N) rowptr[base + 1] = run; run += v1;
    if (base + 2 < N) rowptr[base + 2] = run; run += v2;
    if (base + 3 < N) rowptr[base + 3] = run;
    if (t == 255) partials[blockIdx.x] = sh[255];
}

__global__ void scanB_k(int* partials, int nch) {
    if (threadIdx.x == 0 && blockIdx.x == 0) {
        int run = 0;
        for (int i = 0; i < nch; ++i) { int x = partials[i]; partials[i] = run; run += x; }
        partials[nch] = run;
    }
}

__global__ __launch_bounds__(256) void addoff_k(int* __restrict__ rowptr, const int* __restrict__ partials,
                                                int N, int nch) {
    int t = threadIdx.x;
    int off = partials[blockIdx.x];
    int base = blockIdx.x * 1024;
    for (int i = 0; i < 4; ++i) {
        int idx = base + t + i * 256;
        if (idx < N) rowptr[idx] += off;
    }
    if (blockIdx.x == 0 && t == 0) rowptr[N] = partials[nch];
}

// ---------------- merged prologue: hist + cvt(interleaved) + wprep x2 ----------------
// X interleaved layout: row = 2*Cin shorts; 8-col group g: hi8 at [g*16, g*16+8), lo8 at +8.

__global__ __launch_bounds__(256) void prep_k(
    const int* __restrict__ dst, int* __restrict__ deg, int E, int histB,
    const float* __restrict__ x, unsigned short* __restrict__ Xc, int ngrp, int cvtB,
    const float* __restrict__ Wq1, const float* __restrict__ Wk1,
    const float* __restrict__ Wv1, const float* __restrict__ Ws1,
    unsigned* __restrict__ fhi1, unsigned* __restrict__ flo1, int w1B,
    const float* __restrict__ Wq2, const float* __restrict__ Wk2,
    const float* __restrict__ Wv2, const float* __restrict__ Ws2,
    unsigned* __restrict__ fhi2, unsigned* __restrict__ flo2)
{
    int b = blockIdx.x;
    int tid = threadIdx.x;
    if (b < histB) {
        int e = b * 256 + tid;
        if (e < E) atomicAdd(&deg[dst[e]], 1);
        return;
    }
    b -= histB;
    if (b < cvtB) {
        int gi = b * 256 + tid;   // group of 8 f32 -> hi8|lo8 (32B contiguous)
        if (gi < ngrp) {
            const float* xp = x + (size_t)gi * 8;
            float4 a0 = *(const float4*)xp;
            float4 a1 = *(const float4*)(xp + 4);
            unsigned short* op = Xc + (size_t)gi * 16;
            ushort4 h0, h1, L0, L1;
            h0.x = f2b(a0.x); L0.x = f2b(a0.x - b2f(h0.x));
            h0.y = f2b(a0.y); L0.y = f2b(a0.y - b2f(h0.y));
            h0.z = f2b(a0.z); L0.z = f2b(a0.z - b2f(h0.z));
            h0.w = f2b(a0.w); L0.w = f2b(a0.w - b2f(h0.w));
            h1.x = f2b(a1.x); L1.x = f2b(a1.x - b2f(h1.x));
            h1.y = f2b(a1.y); L1.y = f2b(a1.y - b2f(h1.y));
            h1.z = f2b(a1.z); L1.z = f2b(a1.z - b2f(h1.z));
            h1.w = f2b(a1.w); L1.w = f2b(a1.w - b2f(h1.w));
            *(ushort4*)(op)      = h0;
            *(ushort4*)(op + 4)  = h1;
            *(ushort4*)(op + 8)  = L0;
            *(ushort4*)(op + 12) = L1;
        }
        return;
    }
    b -= cvtB;
    const float *Wq, *Wk, *Wv, *Ws; unsigned *fhi, *flo; int ksteps, idx;
    if (b < w1B) {
        Wq = Wq1; Wk = Wk1; Wv = Wv1; Ws = Ws1; fhi = fhi1; flo = flo1;
        ksteps = 4; idx = b * 256 + tid;
        if (idx >= 26 * 4 * 64 * 4) return;
    } else {
        Wq = Wq2; Wk = Wk2; Wv = Wv2; Ws = Ws2; fhi = fhi2; flo = flo2;
        ksteps = 1; idx = (b - w1B) * 256 + tid;
        if (idx >= 26 * 1 * 64 * 4) return;
    }
    int w = idx & 3;
    int lane = (idx >> 2) & 63;
    int tmp = idx >> 8;
    int kk = tmp % ksteps;
    int t = tmp / ksteps;
    int col = t * 16 + (lane & 15);
    int k0 = kk * 32 + ((lane >> 4) << 3) + (w << 1);
    const float* W; int ow, c;
    if (col < 128)      { W = Wq; ow = 128; c = col; }
    else if (col < 256) { W = Wk; ow = 128; c = col - 128; }
    else if (col < 384) { W = Wv; ow = 128; c = col - 256; }
    else                { W = Ws; ow = 32;  c = col - 384; }
    float v0 = W[(size_t)k0 * ow + c];
    float v1 = W[(size_t)(k0 + 1) * ow + c];
    unsigned short h0 = f2b(v0), h1 = f2b(v1);
    unsigned short l0 = f2b(v0 - b2f(h0)), l1 = f2b(v1 - b2f(h1));
    fhi[idx] = (unsigned)h0 | ((unsigned)h1 << 16);
    flo[idx] = (unsigned)l0 | ((unsigned)l1 << 16);
}

// ---------------- fused Q/K/V/skip projection via bf16 MFMA + fused CSR scatter ----------------
// Flattened grid: blocks [0, qkvsBlocks) do the GEMM (x = fb>>2, y = fb&3);
// blocks [qkvsBlocks, ...) do the CSR scatter (1024 edges/block). The scatter is pure
// memory/atomic latency (R20: 128us, 0.4% VALU) and hides in the GEMM's spare occupancy.
// GEMM: persistent-B (NT=7), zero-barrier row-tile loop, A pipelined one rt ahead.
// Outputs: q bf16, kv rows = [k 128 fp8 | v 128 fp8] (256B), sk f32.

template<int KSTEPS>
__global__ __launch_bounds__(1024) void qkvs_mfma(const unsigned short* __restrict__ Xc,
    int Cin, int N,
    const unsigned* __restrict__ fhi, const unsigned* __restrict__ flo,
    const float* __restrict__ bq, const float* __restrict__ bk,
    const float* __restrict__ bv, const float* __restrict__ bs,
    unsigned short* __restrict__ q, unsigned char* __restrict__ kvb,
    float* __restrict__ sk, int rtPer, int qkvsBlocks,
    const int* __restrict__ srcE, const int* __restrict__ dstE,
    const int* __restrict__ rowptr, int* __restrict__ cnt,
    int* __restrict__ srcid, int E)
{
    constexpr int NT = 7;
    constexpr int NIDX = KSTEPS * NT * 2 * 64;      // 16B units
    __shared__ float4 ldsB[NIDX];

    int fb = blockIdx.x;
    int tid = threadIdx.x;

    if (fb >= qkvsBlocks) {                         // ---- scatter part ----
        int e = (fb - qkvsBlocks) * 1024 + tid;
        if (e < E) {
            int d = dstE[e];
            int pos = rowptr[d] + atomicAdd(&cnt[d], 1);
            srcid[pos] = srcE[e];
        }
        return;
    }

    int bx = fb >> 2, by = fb & 3;
    int lane = tid & 63, wid = tid >> 6;
    int tbase = by * NT;

    for (int u = tid; u < NIDX; u += 1024) {
        int l = u & 63;
        int rest = u >> 6;
        int plane = rest & 1;
        int tt = (rest >> 1) % NT;
        int kk = (rest >> 1) / NT;
        if (tbase + tt < 26) {
            const unsigned* srcp = plane ? flo : fhi;
            size_t so = (((size_t)(tbase + tt) * KSTEPS + kk) * 64 + l) * 4;
            async_copy16(srcp + so, &ldsB[u - l]);
        }
    }
    __syncthreads();   // drains the async fills; only barrier in the kernel

    const int asub2 = ((lane >> 4) << 3) * 2;       // short-offset of this lane's group
    const int rowStride = 2 * Cin;
    int rtTotal = (N + 15) >> 4;
    int rtStart = bx * rtPer;
    int rtEnd = rtStart + rtPer; if (rtEnd > rtTotal) rtEnd = rtTotal;

    auto loadA = [&](int rtX, bf16x8* dstA) {
        int row = rtX * 16 + (lane & 15);
        int rowc = row < N ? row : N - 1;
        const unsigned short* xp = Xc + (size_t)rowc * rowStride + asub2;
#pragma unroll
        for (int kk = 0; kk < KSTEPS; ++kk) {
            dstA[2 * kk]     = *(const bf16x8*)(xp + kk * 64);
            dstA[2 * kk + 1] = *(const bf16x8*)(xp + kk * 64 + 8);
        }
    };

    bf16x8 aCur[2 * KSTEPS];
    int rt0 = rtStart + wid;
    if (rt0 < rtEnd) loadA(rt0, aCur);

    for (int rt = rt0; rt < rtEnd; rt += 16) {
        bf16x8 aNxt[2 * KSTEPS];
        bool hasNext = (rt + 16) < rtEnd;
        if (hasNext) loadA(rt + 16, aNxt);      // prefetch next row-tile's A

        f32x4 acc[NT];
#pragma unroll
        for (int t = 0; t < NT; ++t) acc[t] = (f32x4){0.f, 0.f, 0.f, 0.f};

#pragma unroll
        for (int kk = 0; kk < KSTEPS; ++kk) {
            const float4* base = &ldsB[kk * NT * 2 * 64];
            bf16x8 ah = aCur[2 * kk], al = aCur[2 * kk + 1];
#pragma unroll
            for (int t = 0; t < NT; ++t) {
                bf16x8 bh = *(const bf16x8*)&base[(t * 2 + 0) * 64 + lane];
                bf16x8 bl = *(const bf16x8*)&base[(t * 2 + 1) * 64 + lane];
                acc[t] = mfma16(ah, bh, acc[t]);
                acc[t] = mfma16(al, bh, acc[t]);
                acc[t] = mfma16(ah, bl, acc[t]);
            }
        }

        // ---- store with bias; q bf16, k/v fp8 (kv row 256B), sk f32 ----
#pragma unroll
        for (int t = 0; t < NT; ++t) {
            int col = (tbase + t) * 16 + (lane & 15);
            if (col >= 416) continue;
            int sel; const float* bp; int c;
            if (col < 128)      { sel = 0; bp = bq; c = col; }
            else if (col < 256) { sel = 1; bp = bk; c = col - 128; }
            else if (col < 384) { sel = 2; bp = bv; c = col - 256; }
            else                { sel = 3; bp = bs; c = col - 384; }
            float bias = bp[c];
#pragma unroll
            for (int r = 0; r < 4; ++r) {
                int orow = rt * 16 + ((lane >> 4) << 2) + r;
                if (orow >= N) continue;
                float val = acc[t][r] + bias;
                if (sel == 0)      q[(size_t)orow * 128 + c] = f2b(val);
                else if (sel == 1) kvb[(size_t)orow * 256 + c] = f2e4m3(val);
                else if (sel == 2) kvb[(size_t)orow * 256 + 128 + c] = f2e4m3(val);
                else               sk[(size_t)orow * 32 + c] = val;
            }
        }

        if (hasNext) {
#pragma unroll
            for (int i = 0; i < 2 * KSTEPS; ++i) aCur[i] = aNxt[i];
        }
    }
}

// ---------------- per-node attention over CSR ----------------
// 32 threads per node; kv rows = [k 128 fp8 | v 128 fp8] (256B/src node), q bf16.
// fp8 decode via HARDWARE v_cvt_pk_f32_fp8. No-max softmax, exp2 folded scale, 4-way unroll.
// mode 0: f32 out; mode 1: interleaved hi|lo bf16 out.

__global__ __launch_bounds__(256) void attn_k(const unsigned short* __restrict__ q,
    const unsigned char* __restrict__ kv,
    const float* __restrict__ sk,
    const int* __restrict__ rowptr, const int* __restrict__ srcid,
    float* __restrict__ outF, unsigned short* __restrict__ outC, int mode, int N)
{
    int grp = threadIdx.x >> 5;
    int n = blockIdx.x * 8 + grp;
    if (n >= N) return;
    int l = threadIdx.x & 31;
    int s = l & 7;
    const float c2 = 0.25504233001306574f;   // 1/sqrt(32) * 1/ln(2)

    ushort4 qr = *(const ushort4*)(q + (size_t)n * 128 + l * 4);
    float4 qv = make_float4(b2f(qr.x), b2f(qr.y), b2f(qr.z), b2f(qr.w));
    float4 acc = make_float4(0.f, 0.f, 0.f, 0.f);
    float lsum = 0.f;

    int e0 = rowptr[n], e1 = rowptr[n + 1];
    int e = e0;
    for (; e + 4 <= e1; e += 4) {
        int s0 = srcid[e], s1 = srcid[e + 1], s2 = srcid[e + 2], s3 = srcid[e + 3];
        const unsigned char* b0 = kv + (size_t)s0 * 256;
        const unsigned char* b1 = kv + (size_t)s1 * 256;
        const unsigned char* b2 = kv + (size_t)s2 * 256;
        const unsigned char* b3 = kv + (size_t)s3 * 256;
        unsigned kw0 = *(const unsigned*)(b0 + (l << 2));
        unsigned kw1 = *(const unsigned*)(b1 + (l << 2));
        unsigned kw2 = *(const unsigned*)(b2 + (l << 2));
        unsigned kw3 = *(const unsigned*)(b3 + (l << 2));
        unsigned vw0 = *(const unsigned*)(b0 + 128 + (l << 2));
        unsigned vw1 = *(const unsigned*)(b1 + 128 + (l << 2));
        unsigned vw2 = *(const unsigned*)(b2 + 128 + (l << 2));
        unsigned vw3 = *(const unsigned*)(b3 + 128 + (l << 2));

        float4 k40 = cvt4_fp8(kw0);
        float4 k41 = cvt4_fp8(kw1);
        float4 k42 = cvt4_fp8(kw2);
        float4 k43 = cvt4_fp8(kw3);
        float p0 = qv.x * k40.x + qv.y * k40.y + qv.z * k40.z + qv.w * k40.w;
        float p1 = qv.x * k41.x + qv.y * k41.y + qv.z * k41.z + qv.w * k41.w;
        float p2 = qv.x * k42.x + qv.y * k42.y + qv.z * k42.z + qv.w * k42.w;
        float p3 = qv.x * k43.x + qv.y * k43.y + qv.z * k43.z + qv.w * k43.w;
        p0 += __shfl_xor(p0, 1, 8); p0 += __shfl_xor(p0, 2, 8); p0 += __shfl_xor(p0, 4, 8);
        p1 += __shfl_xor(p1, 1, 8); p1 += __shfl_xor(p1, 2, 8); p1 += __shfl_xor(p1, 4, 8);
        p2 += __shfl_xor(p2, 1, 8); p2 += __shfl_xor(p2, 2, 8); p2 += __shfl_xor(p2, 4, 8);
        p3 += __shfl_xor(p3, 1, 8); p3 += __shfl_xor(p3, 2, 8); p3 += __shfl_xor(p3, 4, 8);
        float ex0 = exp2f(fminf(p0 * c2, 86.f));
        float ex1 = exp2f(fminf(p1 * c2, 86.f));
        float ex2 = exp2f(fminf(p2 * c2, 86.f));
        float ex3 = exp2f(fminf(p3 * c2, 86.f));
        lsum += (ex0 + ex1) + (ex2 + ex3);
        float4 v40 = cvt4_fp8(vw0);
        float4 v41 = cvt4_fp8(vw1);
        float4 v42 = cvt4_fp8(vw2);
        float4 v43 = cvt4_fp8(vw3);
        acc.x += ex0 * v40.x + ex1 * v41.x + ex2 * v42.x + ex3 * v43.x;
        acc.y += ex0 * v40.y + ex1 * v41.y + ex2 * v42.y + ex3 * v43.y;
        acc.z += ex0 * v40.z + ex1 * v41.z + ex2 * v42.z + ex3 * v43.z;
        acc.w += ex0 * v40.w + ex1 * v41.w + ex2 * v42.w + ex3 * v43.w;
    }
    for (; e < e1; ++e) {
        const unsigned char* b0 = kv + (size_t)srcid[e] * 256;
        unsigned kw0 = *(const unsigned*)(b0 + (l << 2));
        unsigned vw0 = *(const unsigned*)(b0 + 128 + (l << 2));
        float4 k40 = cvt4_fp8(kw0);
        float p0 = qv.x * k40.x + qv.y * k40.y + qv.z * k40.z + qv.w * k40.w;
        p0 += __shfl_xor(p0, 1, 8); p0 += __shfl_xor(p0, 2, 8); p0 += __shfl_xor(p0, 4, 8);
        float ex0 = exp2f(fminf(p0 * c2, 86.f));
        lsum += ex0;
        float4 v40 = cvt4_fp8(vw0);
        acc.x += ex0 * v40.x;
        acc.y += ex0 * v40.y;
        acc.z += ex0 * v40.z;
        acc.w += ex0 * v40.w;
    }

    float inv = 0.25f / fmaxf(lsum, 1e-16f);
    float rx = acc.x * inv, ry = acc.y * inv, rz = acc.z * inv, rw = acc.w * inv;
    rx += __shfl_xor(rx, 8, 32);  rx += __shfl_xor(rx, 16, 32);
    ry += __shfl_xor(ry, 8, 32);  ry += __shfl_xor(ry, 16, 32);
    rz += __shfl_xor(rz, 8, 32);  rz += __shfl_xor(rz, 16, 32);
    rw += __shfl_xor(rw, 8, 32);  rw += __shfl_xor(rw, 16, 32);

    if (l < 8) {
        const float* skp = sk + (size_t)n * 32 + s * 4;
        float o0 = fmaxf(rx + skp[0], 0.f), o1 = fmaxf(ry + skp[1], 0.f);
        float o2 = fmaxf(rz + skp[2], 0.f), o3 = fmaxf(rw + skp[3], 0.f);
        if (mode == 0) {
            *(float4*)(outF + (size_t)n * 32 + s * 4) = make_float4(o0, o1, o2, o3);
        } else {
            // interleaved hi|lo: row = 64 shorts, group g=s>>1, off=(s&1)*4
            ushort4 h, L;
            h.x = f2b(o0); L.x = f2b(o0 - b2f(h.x));
            h.y = f2b(o1); L.y = f2b(o1 - b2f(h.y));
            h.z = f2b(o2); L.z = f2b(o2 - b2f(h.z));
            h.w = f2b(o3); L.w = f2b(o3 - b2f(h.w));
            unsigned short* op = outC + (size_t)n * 64 + (s >> 1) * 16 + (s & 1) * 4;
            *(ushort4*)op       = h;
            *(ushort4*)(op + 8) = L;
        }
    }
}

// ---------------- global mean pool (batch is sorted) ----------------

__global__ __launch_bounds__(256) void pool_k(const float* __restrict__ h, const int* __restrict__ batch,
                                              float* __restrict__ out, int N)
{
    int g = blockIdx.x;
    int t = threadIdx.x;
    int lo = 0, hi = N;
    while (lo < hi) { int mid = (lo + hi) >> 1; if (batch[mid] < g) lo = mid + 1; else hi = mid; }
    int start = lo;
    lo = 0; hi = N;
    while (lo < hi) { int mid = (lo + hi) >> 1; if (batch[mid] < g + 1) lo = mid + 1; else hi = mid; }
    int end = lo;
    int c = t & 31, r0 = t >> 5;
    float s = 0.f;
    for (int r = start + r0; r < end; r += 8) s += h[(size_t)r * 32 + c];
    __shared__ float sh[256];
    sh[t] = s;
    __syncthreads();
    if (t < 32) {
        float tot = sh[t] + sh[t + 32] + sh[t + 64] + sh[t + 96]
                  + sh[t + 128] + sh[t + 160] + sh[t + 192] + sh[t + 224];
        float cnt = (float)(end - start);
        out[(size_t)g * 32 + t] = tot / fmaxf(cnt, 1.f);
    }
}

// ---------------- launch ----------------

extern "C" void kernel_launch(void* const* d_in, const int* in_sizes, int n_in,
                              void* d_out, int out_size, void* d_ws, size_t ws_size,
                              hipStream_t stream) {
    const float* x   = (const float*)d_in[0];
    const int* ei    = (const int*)d_in[1];
    const int* batch = (const int*)d_in[2];
    const float *Wq1 = (const float*)d_in[3],  *bq1 = (const float*)d_in[4];
    const float *Wk1 = (const float*)d_in[5],  *bk1 = (const float*)d_in[6];
    const float *Wv1 = (const float*)d_in[7],  *bv1 = (const float*)d_in[8];
    const float *Ws1 = (const float*)d_in[9],  *bs1 = (const float*)d_in[10];
    const float *Wq2 = (const float*)d_in[11], *bq2 = (const float*)d_in[12];
    const float *Wk2 = (const float*)d_in[13], *bk2 = (const float*)d_in[14];
    const float *Wv2 = (const float*)d_in[15], *bv2 = (const float*)d_in[16];
    const float *Ws2 = (const float*)d_in[17], *bs2 = (const float*)d_in[18];
    float* out = (float*)d_out;

    int N = in_sizes[0] / 128;
    int E = in_sizes[1] / 2;
    const int* src = ei;
    const int* dst = ei + E;

    char* ws = (char*)d_ws;
    size_t off = 0;
    auto alloc = [&](size_t bytes) -> void* {
        void* p = ws + off;
        off += (bytes + 255) & ~(size_t)255;
        return p;
    };
    int* deg      = (int*)alloc((size_t)N * 4);
    int* cnt      = (int*)alloc((size_t)N * 4);
    int* rowptr   = (int*)alloc(((size_t)N + 1) * 4);
    int* partials = (int*)alloc(4096);
    int* srcid    = (int*)alloc((size_t)E * 4);
    unsigned* fhi1 = (unsigned*)alloc(26 * 4 * 64 * 4 * 4);
    unsigned* flo1 = (unsigned*)alloc(26 * 4 * 64 * 4 * 4);
    unsigned* fhi2 = (unsigned*)alloc(26 * 1 * 64 * 4 * 4);
    unsigned* flo2 = (unsigned*)alloc(26 * 1 * 64 * 4 * 4);
    unsigned short* Xc  = (unsigned short*)alloc((size_t)N * 256 * 2);   // interleaved hi|lo
    unsigned short* q   = (unsigned short*)alloc((size_t)N * 128 * 2);
    unsigned char* kvb  = (unsigned char*)alloc((size_t)N * 256);
    float* sk     = (float*)alloc((size_t)N * 32 * 4);
    unsigned short* h1c = (unsigned short*)alloc((size_t)N * 64 * 2);    // interleaved hi|lo
    float* h2     = (float*)alloc((size_t)N * 32 * 4);

    hipMemsetAsync(deg, 0, (size_t)N * 4, stream);
    hipMemsetAsync(cnt, 0, (size_t)N * 4, stream);

    int histB = (E + 255) / 256;
    int ngrp = N * 16;                       // N*128/8 groups
    int cvtB = (ngrp + 255) / 256;
    int w1B = (26 * 4 * 64 * 4 + 255) / 256;
    int w2B = (26 * 1 * 64 * 4 + 255) / 256;
    prep_k<<<histB + cvtB + w1B + w2B, 256, 0, stream>>>(
        dst, deg, E, histB,
        x, Xc, ngrp, cvtB,
        Wq1, Wk1, Wv1, Ws1, fhi1, flo1, w1B,
        Wq2, Wk2, Wv2, Ws2, fhi2, flo2);

    int nch = (N + 1023) / 1024;
    scanA_k<<<nch, 256, 0, stream>>>(deg, rowptr, partials, N);
    scanB_k<<<1, 64, 0, stream>>>(partials, nch);
    addoff_k<<<nch, 256, 0, stream>>>(rowptr, partials, N, nch);

    int rtTotal = (N + 15) / 16;
    int rtPer = (rtTotal + 127) / 128;
    int scatB = (E + 1023) / 1024;
    // layer 1: GEMM blocks [0,512) + scatter blocks [512, 512+scatB)
    qkvs_mfma<4><<<512 + scatB, 1024, 0, stream>>>(Xc, 128, N, fhi1, flo1,
        bq1, bk1, bv1, bs1, q, kvb, sk, rtPer, 512,
        src, dst, rowptr, cnt, srcid, E);
    attn_k<<<(N + 7) / 8, 256, 0, stream>>>(q, kvb, sk, rowptr, srcid,
        nullptr, h1c, 1, N);
    // layer 2: no scatter blocks
    qkvs_mfma<1><<<512, 1024, 0, stream>>>(h1c, 32, N, fhi2, flo2,
        bq2, bk2, bv2, bs2, q, kvb, sk, rtPer, 512,
        nullptr, nullptr, nullptr, nullptr, nullptr, 0);
    attn_k<<<(N + 7) / 8, 256, 0, stream>>>(q, kvb, sk, rowptr, srcid,
        h2, nullptr, 0, N);
    pool_k<<<512, 256, 0, stream>>>(h2, batch, out, N);
}

// Round 23
// 479.678 us; speedup vs baseline: 1.2471x; 1.0220x over previous
//
#include <hip/hip_runtime.h>
#include <math.h>

typedef __attribute__((ext_vector_type(8))) short bf16x8;
typedef __attribute__((ext_vector_type(4))) float f32x4;
typedef __attribute__((ext_vector_type(2))) float f32x2;

__device__ __forceinline__ float b2f(unsigned short u) {
    union { unsigned u32; float f; } x; x.u32 = (unsigned)u << 16; return x.f;
}
__device__ __forceinline__ unsigned short f2b(float f) {
    union { float f; unsigned u32; } x; x.f = f;
    unsigned u = x.u32;
    unsigned r = (u + 0x7fffu + ((u >> 16) & 1u)) >> 16;   // RNE
    return (unsigned short)r;
}

// f32 -> OCP e4m3fn, RNE, clamp to +-448, subnormals exact.
__device__ __forceinline__ unsigned char f2e4m3(float f) {
    union { float f; unsigned u; } x; x.f = f;
    unsigned s = (x.u >> 24) & 0x80;
    x.u &= 0x7fffffff;
    if (!(x.f == x.f)) return (unsigned char)(s | 0x7e);
    if (x.f >= 448.f) return (unsigned char)(s | 0x7e);
    if (x.f < 0.015625f) {                       // subnormal: m * 2^-9, RNE
        int m = (int)rintf(x.f * 512.f);
        if (m >= 8) return (unsigned char)(s | 0x08);
        return (unsigned char)(s | (unsigned)m);
    }
    unsigned exp = x.u >> 23;
    unsigned mant = x.u & 0x7fffff;
    unsigned m3 = mant >> 20;
    unsigned rb = (mant >> 19) & 1u;
    unsigned sticky = (mant & 0x7ffffu) ? 1u : 0u;
    m3 += rb & (sticky | (m3 & 1u));
    if (m3 == 8) { m3 = 0; exp++; }
    unsigned e4 = exp - 120;                     // bias 7
    if (e4 >= 15 && m3 > 6) { e4 = 15; m3 = 6; } // stay <= 448
    return (unsigned char)(s | (e4 << 3) | m3);
}

// hardware decode: 4 packed OCP-e4m3 bytes -> 4 f32 (2 x v_cvt_pk_f32_fp8)
__device__ __forceinline__ float4 cvt4_fp8(unsigned w) {
    f32x2 lo = __builtin_amdgcn_cvt_pk_f32_fp8((int)w, false);
    f32x2 hi = __builtin_amdgcn_cvt_pk_f32_fp8((int)w, true);
    return make_float4(lo[0], lo[1], hi[0], hi[1]);
}

__device__ __forceinline__ f32x4 mfma16(bf16x8 a, bf16x8 b, f32x4 c) {
    return __builtin_amdgcn_mfma_f32_16x16x32_bf16(a, b, c, 0, 0, 0);
}

// async global->LDS, 16B per lane: lds dest = uniform base + lane*16, global src per-lane.
__device__ __forceinline__ void async_copy16(const unsigned* g, void* l) {
    __builtin_amdgcn_global_load_lds(
        (const __attribute__((address_space(1))) unsigned*)g,
        (__attribute__((address_space(3))) unsigned*)l, 16, 0, 0);
}

// ---------------- CSR scan pieces ----------------

__global__ __launch_bounds__(256) void scanA_k(const int* __restrict__ deg, int* __restrict__ rowptr,
                                               int* __restrict__ partials, int N) {
    __shared__ int sh[256];
    int t = threadIdx.x;
    int base = blockIdx.x * 1024 + t * 4;
    int v0 = 0, v1 = 0, v2 = 0, v3 = 0;
    if (base + 0 < N) v0 = deg[base + 0];
    if (base + 1 < N) v1 = deg[base + 1];
    if (base + 2 < N) v2 = deg[base + 2];
    if (base + 3 < N) v3 = deg[base + 3];
    sh[t] = v0 + v1 + v2 + v3;
    __syncthreads();
    for (int off = 1; off < 256; off <<= 1) {
        int add = (t >= off) ? sh[t - off] : 0;
        __syncthreads();
        sh[t] += add;
        __syncthreads();
    }
    int run = (t > 0) ? sh[t - 1] : 0;
    if (base + 0 < N) rowptr[base + 0] = run; run += v0;
    if (base + 1 < N) rowptr[base + 1] = run; run += v1;
    if (base + 2 < N) rowptr[base + 2] = run; run += v2;
    if (base + 3 < N) rowptr[base + 3] = run;
    if (t == 255) partials[blockIdx.x] = sh[255];
}

__global__ void scanB_k(int* partials, int nch) {
    if (threadIdx.x == 0 && blockIdx.x == 0) {
        int run = 0;
        for (int i = 0; i < nch; ++i) { int x = partials[i]; partials[i] = run; run += x; }
        partials[nch] = run;
    }
}

__global__ __launch_bounds__(256) void addoff_k(int* __restrict__ rowptr, const int* __restrict__ partials,
                                                int N, int nch) {
    int t = threadIdx.x;
    int off = partials[blockIdx.x];
    int base = blockIdx.x * 1024;
    for (int i = 0; i < 4; ++i) {
        int idx = base + t + i * 256;
        if (idx < N) rowptr[idx] += off;
    }
    if (blockIdx.x == 0 && t == 0) rowptr[N] = partials[nch];
}

// ---------------- merged prologue: hist + cvt(interleaved) + wprep x2 ----------------
// X interleaved layout: row = 2*Cin shorts; 8-col group g: hi8 at [g*16, g*16+8), lo8 at +8.

__global__ __launch_bounds__(256) void prep_k(
    const int* __restrict__ dst, int* __restrict__ deg, int E, int histB,
    const float* __restrict__ x, unsigned short* __restrict__ Xc, int ngrp, int cvtB,
    const float* __restrict__ Wq1, const float* __restrict__ Wk1,
    const float* __restrict__ Wv1, const float* __restrict__ Ws1,
    unsigned* __restrict__ fhi1, unsigned* __restrict__ flo1, int w1B,
    const float* __restrict__ Wq2, const float* __restrict__ Wk2,
    const float* __restrict__ Wv2, const float* __restrict__ Ws2,
    unsigned* __restrict__ fhi2, unsigned* __restrict__ flo2)
{
    int b = blockIdx.x;
    int tid = threadIdx.x;
    if (b < histB) {
        int e = b * 256 + tid;
        if (e < E) atomicAdd(&deg[dst[e]], 1);
        return;
    }
    b -= histB;
    if (b < cvtB) {
        int gi = b * 256 + tid;   // group of 8 f32 -> hi8|lo8 (32B contiguous)
        if (gi < ngrp) {
            const float* xp = x + (size_t)gi * 8;
            float4 a0 = *(const float4*)xp;
            float4 a1 = *(const float4*)(xp + 4);
            unsigned short* op = Xc + (size_t)gi * 16;
            ushort4 h0, h1, L0, L1;
            h0.x = f2b(a0.x); L0.x = f2b(a0.x - b2f(h0.x));
            h0.y = f2b(a0.y); L0.y = f2b(a0.y - b2f(h0.y));
            h0.z = f2b(a0.z); L0.z = f2b(a0.z - b2f(h0.z));
            h0.w = f2b(a0.w); L0.w = f2b(a0.w - b2f(h0.w));
            h1.x = f2b(a1.x); L1.x = f2b(a1.x - b2f(h1.x));
            h1.y = f2b(a1.y); L1.y = f2b(a1.y - b2f(h1.y));
            h1.z = f2b(a1.z); L1.z = f2b(a1.z - b2f(h1.z));
            h1.w = f2b(a1.w); L1.w = f2b(a1.w - b2f(h1.w));
            *(ushort4*)(op)      = h0;
            *(ushort4*)(op + 4)  = h1;
            *(ushort4*)(op + 8)  = L0;
            *(ushort4*)(op + 12) = L1;
        }
        return;
    }
    b -= cvtB;
    const float *Wq, *Wk, *Wv, *Ws; unsigned *fhi, *flo; int ksteps, idx;
    if (b < w1B) {
        Wq = Wq1; Wk = Wk1; Wv = Wv1; Ws = Ws1; fhi = fhi1; flo = flo1;
        ksteps = 4; idx = b * 256 + tid;
        if (idx >= 26 * 4 * 64 * 4) return;
    } else {
        Wq = Wq2; Wk = Wk2; Wv = Wv2; Ws = Ws2; fhi = fhi2; flo = flo2;
        ksteps = 1; idx = (b - w1B) * 256 + tid;
        if (idx >= 26 * 1 * 64 * 4) return;
    }
    int w = idx & 3;
    int lane = (idx >> 2) & 63;
    int tmp = idx >> 8;
    int kk = tmp % ksteps;
    int t = tmp / ksteps;
    int col = t * 16 + (lane & 15);
    int k0 = kk * 32 + ((lane >> 4) << 3) + (w << 1);
    const float* W; int ow, c;
    if (col < 128)      { W = Wq; ow = 128; c = col; }
    else if (col < 256) { W = Wk; ow = 128; c = col - 128; }
    else if (col < 384) { W = Wv; ow = 128; c = col - 256; }
    else                { W = Ws; ow = 32;  c = col - 384; }
    float v0 = W[(size_t)k0 * ow + c];
    float v1 = W[(size_t)(k0 + 1) * ow + c];
    unsigned short h0 = f2b(v0), h1 = f2b(v1);
    unsigned short l0 = f2b(v0 - b2f(h0)), l1 = f2b(v1 - b2f(h1));
    fhi[idx] = (unsigned)h0 | ((unsigned)h1 << 16);
    flo[idx] = (unsigned)l0 | ((unsigned)l1 << 16);
}

// ---------------- fused Q/K/V/skip projection via bf16 MFMA + fused CSR scatter ----------------
// Flattened grid, 512-thread blocks: blocks [0, qkvsBlocks) do the GEMM (x=fb>>2, y=fb&3),
// 8 waves each -> 2 blocks/CU = 16 wave slots, leaving 16 free so the scatter blocks
// [qkvsBlocks,...) (512 edges each, pure latency) CO-RESIDE from the start (R21's 1024-thr
// blocks filled all 32 slots and the scatter serialized at the tail).
// kv rows word-interleaved: [k4|v4] per 8B pair -> attn issues ONE 8B load per edge-lane.
// Outputs: q bf16, kv rows 256B interleaved fp8, sk f32.

template<int KSTEPS>
__global__ __launch_bounds__(512) void qkvs_mfma(const unsigned short* __restrict__ Xc,
    int Cin, int N,
    const unsigned* __restrict__ fhi, const unsigned* __restrict__ flo,
    const float* __restrict__ bq, const float* __restrict__ bk,
    const float* __restrict__ bv, const float* __restrict__ bs,
    unsigned short* __restrict__ q, unsigned char* __restrict__ kvb,
    float* __restrict__ sk, int rtPer, int qkvsBlocks,
    const int* __restrict__ srcE, const int* __restrict__ dstE,
    const int* __restrict__ rowptr, int* __restrict__ cnt,
    int* __restrict__ srcid, int E)
{
    constexpr int NT = 7;
    constexpr int NIDX = KSTEPS * NT * 2 * 64;      // 16B units
    __shared__ float4 ldsB[NIDX];

    int fb = blockIdx.x;
    int tid = threadIdx.x;

    if (fb >= qkvsBlocks) {                         // ---- scatter part ----
        int e = (fb - qkvsBlocks) * 512 + tid;
        if (e < E) {
            int d = dstE[e];
            int pos = rowptr[d] + atomicAdd(&cnt[d], 1);
            srcid[pos] = srcE[e];
        }
        return;
    }

    int bx = fb >> 2, by = fb & 3;
    int lane = tid & 63, wid = tid >> 6;            // 8 waves
    int tbase = by * NT;

    for (int u = tid; u < NIDX; u += 512) {
        int l = u & 63;
        int rest = u >> 6;
        int plane = rest & 1;
        int tt = (rest >> 1) % NT;
        int kk = (rest >> 1) / NT;
        if (tbase + tt < 26) {
            const unsigned* srcp = plane ? flo : fhi;
            size_t so = (((size_t)(tbase + tt) * KSTEPS + kk) * 64 + l) * 4;
            async_copy16(srcp + so, &ldsB[u - l]);
        }
    }
    __syncthreads();   // drains the async fills; only barrier in the kernel

    const int asub2 = ((lane >> 4) << 3) * 2;       // short-offset of this lane's group
    const int rowStride = 2 * Cin;
    int rtTotal = (N + 15) >> 4;
    int rtStart = bx * rtPer;
    int rtEnd = rtStart + rtPer; if (rtEnd > rtTotal) rtEnd = rtTotal;

    auto loadA = [&](int rtX, bf16x8* dstA) {
        int row = rtX * 16 + (lane & 15);
        int rowc = row < N ? row : N - 1;
        const unsigned short* xp = Xc + (size_t)rowc * rowStride + asub2;
#pragma unroll
        for (int kk = 0; kk < KSTEPS; ++kk) {
            dstA[2 * kk]     = *(const bf16x8*)(xp + kk * 64);
            dstA[2 * kk + 1] = *(const bf16x8*)(xp + kk * 64 + 8);
        }
    };

    bf16x8 aCur[2 * KSTEPS];
    int rt0 = rtStart + wid;
    if (rt0 < rtEnd) loadA(rt0, aCur);

    for (int rt = rt0; rt < rtEnd; rt += 8) {
        bf16x8 aNxt[2 * KSTEPS];
        bool hasNext = (rt + 8) < rtEnd;
        if (hasNext) loadA(rt + 8, aNxt);       // prefetch next row-tile's A

        f32x4 acc[NT];
#pragma unroll
        for (int t = 0; t < NT; ++t) acc[t] = (f32x4){0.f, 0.f, 0.f, 0.f};

#pragma unroll
        for (int kk = 0; kk < KSTEPS; ++kk) {
            const float4* base = &ldsB[kk * NT * 2 * 64];
            bf16x8 ah = aCur[2 * kk], al = aCur[2 * kk + 1];
#pragma unroll
            for (int t = 0; t < NT; ++t) {
                bf16x8 bh = *(const bf16x8*)&base[(t * 2 + 0) * 64 + lane];
                bf16x8 bl = *(const bf16x8*)&base[(t * 2 + 1) * 64 + lane];
                acc[t] = mfma16(ah, bh, acc[t]);
                acc[t] = mfma16(al, bh, acc[t]);
                acc[t] = mfma16(ah, bl, acc[t]);
            }
        }

        // ---- store with bias; q bf16, kv word-interleaved fp8 (row 256B), sk f32 ----
#pragma unroll
        for (int t = 0; t < NT; ++t) {
            int col = (tbase + t) * 16 + (lane & 15);
            if (col >= 416) continue;
            int sel; const float* bp; int c;
            if (col < 128)      { sel = 0; bp = bq; c = col; }
            else if (col < 256) { sel = 1; bp = bk; c = col - 128; }
            else if (col < 384) { sel = 2; bp = bv; c = col - 256; }
            else                { sel = 3; bp = bs; c = col - 384; }
            float bias = bp[c];
#pragma unroll
            for (int r = 0; r < 4; ++r) {
                int orow = rt * 16 + ((lane >> 4) << 2) + r;
                if (orow >= N) continue;
                float val = acc[t][r] + bias;
                if (sel == 0)      q[(size_t)orow * 128 + c] = f2b(val);
                else if (sel == 1) kvb[(size_t)orow * 256 + (c >> 2) * 8 + (c & 3)] = f2e4m3(val);
                else if (sel == 2) kvb[(size_t)orow * 256 + (c >> 2) * 8 + 4 + (c & 3)] = f2e4m3(val);
                else               sk[(size_t)orow * 32 + c] = val;
            }
        }

        if (hasNext) {
#pragma unroll
            for (int i = 0; i < 2 * KSTEPS; ++i) aCur[i] = aNxt[i];
        }
    }
}

// ---------------- per-node attention over CSR ----------------
// 32 threads per node; kv rows 256B word-interleaved fp8 ([k4|v4] per 8B), q bf16.
// ONE 8B load per edge-lane (vs 2 dword loads before). HW fp8 decode, no-max softmax,
// exp2 folded scale, 4-way unroll. mode 0: f32 out; mode 1: interleaved hi|lo bf16 out.

__global__ __launch_bounds__(256) void attn_k(const unsigned short* __restrict__ q,
    const unsigned char* __restrict__ kv,
    const float* __restrict__ sk,
    const int* __restrict__ rowptr, const int* __restrict__ srcid,
    float* __restrict__ outF, unsigned short* __restrict__ outC, int mode, int N)
{
    int grp = threadIdx.x >> 5;
    int n = blockIdx.x * 8 + grp;
    if (n >= N) return;
    int l = threadIdx.x & 31;
    int s = l & 7;
    const float c2 = 0.25504233001306574f;   // 1/sqrt(32) * 1/ln(2)

    ushort4 qr = *(const ushort4*)(q + (size_t)n * 128 + l * 4);
    float4 qv = make_float4(b2f(qr.x), b2f(qr.y), b2f(qr.z), b2f(qr.w));
    float4 acc = make_float4(0.f, 0.f, 0.f, 0.f);
    float lsum = 0.f;

    int e0 = rowptr[n], e1 = rowptr[n + 1];
    int e = e0;
    for (; e + 4 <= e1; e += 4) {
        int s0 = srcid[e], s1 = srcid[e + 1], s2 = srcid[e + 2], s3 = srcid[e + 3];
        uint2 kv0 = *(const uint2*)(kv + (size_t)s0 * 256 + (l << 3));
        uint2 kv1 = *(const uint2*)(kv + (size_t)s1 * 256 + (l << 3));
        uint2 kv2 = *(const uint2*)(kv + (size_t)s2 * 256 + (l << 3));
        uint2 kv3 = *(const uint2*)(kv + (size_t)s3 * 256 + (l << 3));

        float4 k40 = cvt4_fp8(kv0.x);
        float4 k41 = cvt4_fp8(kv1.x);
        float4 k42 = cvt4_fp8(kv2.x);
        float4 k43 = cvt4_fp8(kv3.x);
        float p0 = qv.x * k40.x + qv.y * k40.y + qv.z * k40.z + qv.w * k40.w;
        float p1 = qv.x * k41.x + qv.y * k41.y + qv.z * k41.z + qv.w * k41.w;
        float p2 = qv.x * k42.x + qv.y * k42.y + qv.z * k42.z + qv.w * k42.w;
        float p3 = qv.x * k43.x + qv.y * k43.y + qv.z * k43.z + qv.w * k43.w;
        p0 += __shfl_xor(p0, 1, 8); p0 += __shfl_xor(p0, 2, 8); p0 += __shfl_xor(p0, 4, 8);
        p1 += __shfl_xor(p1, 1, 8); p1 += __shfl_xor(p1, 2, 8); p1 += __shfl_xor(p1, 4, 8);
        p2 += __shfl_xor(p2, 1, 8); p2 += __shfl_xor(p2, 2, 8); p2 += __shfl_xor(p2, 4, 8);
        p3 += __shfl_xor(p3, 1, 8); p3 += __shfl_xor(p3, 2, 8); p3 += __shfl_xor(p3, 4, 8);
        float ex0 = exp2f(fminf(p0 * c2, 86.f));
        float ex1 = exp2f(fminf(p1 * c2, 86.f));
        float ex2 = exp2f(fminf(p2 * c2, 86.f));
        float ex3 = exp2f(fminf(p3 * c2, 86.f));
        lsum += (ex0 + ex1) + (ex2 + ex3);
        float4 v40 = cvt4_fp8(kv0.y);
        float4 v41 = cvt4_fp8(kv1.y);
        float4 v42 = cvt4_fp8(kv2.y);
        float4 v43 = cvt4_fp8(kv3.y);
        acc.x += ex0 * v40.x + ex1 * v41.x + ex2 * v42.x + ex3 * v43.x;
        acc.y += ex0 * v40.y + ex1 * v41.y + ex2 * v42.y + ex3 * v43.y;
        acc.z += ex0 * v40.z + ex1 * v41.z + ex2 * v42.z + ex3 * v43.z;
        acc.w += ex0 * v40.w + ex1 * v41.w + ex2 * v42.w + ex3 * v43.w;
    }
    for (; e < e1; ++e) {
        uint2 kv0 = *(const uint2*)(kv + (size_t)srcid[e] * 256 + (l << 3));
        float4 k40 = cvt4_fp8(kv0.x);
        float p0 = qv.x * k40.x + qv.y * k40.y + qv.z * k40.z + qv.w * k40.w;
        p0 += __shfl_xor(p0, 1, 8); p0 += __shfl_xor(p0, 2, 8); p0 += __shfl_xor(p0, 4, 8);
        float ex0 = exp2f(fminf(p0 * c2, 86.f));
        lsum += ex0;
        float4 v40 = cvt4_fp8(kv0.y);
        acc.x += ex0 * v40.x;
        acc.y += ex0 * v40.y;
        acc.z += ex0 * v40.z;
        acc.w += ex0 * v40.w;
    }

    float inv = 0.25f / fmaxf(lsum, 1e-16f);
    float rx = acc.x * inv, ry = acc.y * inv, rz = acc.z * inv, rw = acc.w * inv;
    rx += __shfl_xor(rx, 8, 32);  rx += __shfl_xor(rx, 16, 32);
    ry += __shfl_xor(ry, 8, 32);  ry += __shfl_xor(ry, 16, 32);
    rz += __shfl_xor(rz, 8, 32);  rz += __shfl_xor(rz, 16, 32);
    rw += __shfl_xor(rw, 8, 32);  rw += __shfl_xor(rw, 16, 32);

    if (l < 8) {
        const float* skp = sk + (size_t)n * 32 + s * 4;
        float o0 = fmaxf(rx + skp[0], 0.f), o1 = fmaxf(ry + skp[1], 0.f);
        float o2 = fmaxf(rz + skp[2], 0.f), o3 = fmaxf(rw + skp[3], 0.f);
        if (mode == 0) {
            *(float4*)(outF + (size_t)n * 32 + s * 4) = make_float4(o0, o1, o2, o3);
        } else {
            // interleaved hi|lo: row = 64 shorts, group g=s>>1, off=(s&1)*4
            ushort4 h, L;
            h.x = f2b(o0); L.x = f2b(o0 - b2f(h.x));
            h.y = f2b(o1); L.y = f2b(o1 - b2f(h.y));
            h.z = f2b(o2); L.z = f2b(o2 - b2f(h.z));
            h.w = f2b(o3); L.w = f2b(o3 - b2f(h.w));
            unsigned short* op = outC + (size_t)n * 64 + (s >> 1) * 16 + (s & 1) * 4;
            *(ushort4*)op       = h;
            *(ushort4*)(op + 8) = L;
        }
    }
}

// ---------------- global mean pool (batch is sorted) ----------------

__global__ __launch_bounds__(256) void pool_k(const float* __restrict__ h, const int* __restrict__ batch,
                                              float* __restrict__ out, int N)
{
    int g = blockIdx.x;
    int t = threadIdx.x;
    int lo = 0, hi = N;
    while (lo < hi) { int mid = (lo + hi) >> 1; if (batch[mid] < g) lo = mid + 1; else hi = mid; }
    int start = lo;
    lo = 0; hi = N;
    while (lo < hi) { int mid = (lo + hi) >> 1; if (batch[mid] < g + 1) lo = mid + 1; else hi = mid; }
    int end = lo;
    int c = t & 31, r0 = t >> 5;
    float s = 0.f;
    for (int r = start + r0; r < end; r += 8) s += h[(size_t)r * 32 + c];
    __shared__ float sh[256];
    sh[t] = s;
    __syncthreads();
    if (t < 32) {
        float tot = sh[t] + sh[t + 32] + sh[t + 64] + sh[t + 96]
                  + sh[t + 128] + sh[t + 160] + sh[t + 192] + sh[t + 224];
        float cnt = (float)(end - start);
        out[(size_t)g * 32 + t] = tot / fmaxf(cnt, 1.f);
    }
}

// ---------------- launch ----------------

extern "C" void kernel_launch(void* const* d_in, const int* in_sizes, int n_in,
                              void* d_out, int out_size, void* d_ws, size_t ws_size,
                              hipStream_t stream) {
    const float* x   = (const float*)d_in[0];
    const int* ei    = (const int*)d_in[1];
    const int* batch = (const int*)d_in[2];
    const float *Wq1 = (const float*)d_in[3],  *bq1 = (const float*)d_in[4];
    const float *Wk1 = (const float*)d_in[5],  *bk1 = (const float*)d_in[6];
    const float *Wv1 = (const float*)d_in[7],  *bv1 = (const float*)d_in[8];
    const float *Ws1 = (const float*)d_in[9],  *bs1 = (const float*)d_in[10];
    const float *Wq2 = (const float*)d_in[11], *bq2 = (const float*)d_in[12];
    const float *Wk2 = (const float*)d_in[13], *bk2 = (const float*)d_in[14];
    const float *Wv2 = (const float*)d_in[15], *bv2 = (const float*)d_in[16];
    const float *Ws2 = (const float*)d_in[17], *bs2 = (const float*)d_in[18];
    float* out = (float*)d_out;

    int N = in_sizes[0] / 128;
    int E = in_sizes[1] / 2;
    const int* src = ei;
    const int* dst = ei + E;

    char* ws = (char*)d_ws;
    size_t off = 0;
    auto alloc = [&](size_t bytes) -> void* {
        void* p = ws + off;
        off += (bytes + 255) & ~(size_t)255;
        return p;
    };
    int* deg      = (int*)alloc((size_t)N * 4);
    int* cnt      = (int*)alloc((size_t)N * 4);
    int* rowptr   = (int*)alloc(((size_t)N + 1) * 4);
    int* partials = (int*)alloc(4096);
    int* srcid    = (int*)alloc((size_t)E * 4);
    unsigned* fhi1 = (unsigned*)alloc(26 * 4 * 64 * 4 * 4);
    unsigned* flo1 = (unsigned*)alloc(26 * 4 * 64 * 4 * 4);
    unsigned* fhi2 = (unsigned*)alloc(26 * 1 * 64 * 4 * 4);
    unsigned* flo2 = (unsigned*)alloc(26 * 1 * 64 * 4 * 4);
    unsigned short* Xc  = (unsigned short*)alloc((size_t)N * 256 * 2);   // interleaved hi|lo
    unsigned short* q   = (unsigned short*)alloc((size_t)N * 128 * 2);
    unsigned char* kvb  = (unsigned char*)alloc((size_t)N * 256);
    float* sk     = (float*)alloc((size_t)N * 32 * 4);
    unsigned short* h1c = (unsigned short*)alloc((size_t)N * 64 * 2);    // interleaved hi|lo
    float* h2     = (float*)alloc((size_t)N * 32 * 4);

    hipMemsetAsync(deg, 0, (size_t)N * 4, stream);
    hipMemsetAsync(cnt, 0, (size_t)N * 4, stream);

    int histB = (E + 255) / 256;
    int ngrp = N * 16;                       // N*128/8 groups
    int cvtB = (ngrp + 255) / 256;
    int w1B = (26 * 4 * 64 * 4 + 255) / 256;
    int w2B = (26 * 1 * 64 * 4 + 255) / 256;
    prep_k<<<histB + cvtB + w1B + w2B, 256, 0, stream>>>(
        dst, deg, E, histB,
        x, Xc, ngrp, cvtB,
        Wq1, Wk1, Wv1, Ws1, fhi1, flo1, w1B,
        Wq2, Wk2, Wv2, Ws2, fhi2, flo2);

    int nch = (N + 1023) / 1024;
    scanA_k<<<nch, 256, 0, stream>>>(deg, rowptr, partials, N);
    scanB_k<<<1, 64, 0, stream>>>(partials, nch);
    addoff_k<<<nch, 256, 0, stream>>>(rowptr, partials, N, nch);

    int rtTotal = (N + 15) / 16;
    int rtPer = (rtTotal + 127) / 128;
    int scatB = (E + 511) / 512;
    // layer 1: GEMM blocks [0,512) + scatter blocks [512, 512+scatB)
    qkvs_mfma<4><<<512 + scatB, 512, 0, stream>>>(Xc, 128, N, fhi1, flo1,
        bq1, bk1, bv1, bs1, q, kvb, sk, rtPer, 512,
        src, dst, rowptr, cnt, srcid, E);
    attn_k<<<(N + 7) / 8, 256, 0, stream>>>(q, kvb, sk, rowptr, srcid,
        nullptr, h1c, 1, N);
    // layer 2: no scatter blocks
    qkvs_mfma<1><<<512, 512, 0, stream>>>(h1c, 32, N, fhi2, flo2,
        bq2, bk2, bv2, bs2, q, kvb, sk, rtPer, 512,
        nullptr, nullptr, nullptr, nullptr, nullptr, 0);
    attn_k<<<(N + 7) / 8, 256, 0, stream>>>(q, kvb, sk, rowptr, srcid,
        h2, nullptr, 0, N);
    pool_k<<<512, 256, 0, stream>>>(h2, batch, out, N);
}